// Round 1
// baseline (24922.772 us; speedup 1.0000x reference)
//
#include <hip/hip_runtime.h>
#include <hip/hip_cooperative_groups.h>

namespace cg = cooperative_groups;

typedef _Float16 half8 __attribute__((ext_vector_type(8)));
typedef _Float16 half4 __attribute__((ext_vector_type(4)));
typedef float floatx4 __attribute__((ext_vector_type(4)));

static constexpr int BATCH = 1024;
static constexpr int NIN   = 512;    // in_features
static constexpr int MOUT  = 1024;   // out_features
static constexpr float LAMBD = 0.2f;
static constexpr float TOLF  = 1e-4f;
static constexpr int MAX_ITERS = 100;
static constexpr int MM = BATCH * MOUT;   // 1M elements

// Fragment-swizzled layout for 16x16x32 MFMA operands (A: rows, B: cols), f16:
//   flat = ((tile16*32 + kchunk32)*64 + lane)*8 + elem
//   lane = (idx&15) | (((k>>3)&3)<<4), elem = k&7
// One (tile16, k32) fragment = 1 KB contiguous chunk in lane order, so a wave
// stages it with a single global_load_lds width-16 (wave-uniform base+lane*16)
// and loads it with one ds_read_b128 per lane.
__device__ __forceinline__ size_t swz(int idx, int k) {
    return ((((size_t)(idx >> 4) * 32 + (k >> 5)) * 64 +
             ((idx & 15) | (((k >> 3) & 3) << 4))) << 3) + (k & 7);
}

__device__ __forceinline__ float shrinkf(float t) {
    float a = fabsf(t) - LAMBD;
    return a > 0.f ? copysignf(a, t) : 0.f;
}

// ---------------------------------------------------------------------------
// zero-init: t, enc, dec, swizzled enc halves, solved (+nsolved)
// ---------------------------------------------------------------------------
__global__ __launch_bounds__(256) void zero_init(float* t, float* enc,
                                                 float* dec, float* ench_f,
                                                 float* encl_f, int* solved) {
    int i = blockIdx.x * 256 + threadIdx.x;
    if (i < MM) { t[i] = 0.f; enc[i] = 0.f; }
    if (i < MM / 2) { dec[i] = 0.f; ench_f[i] = 0.f; encl_f[i] = 0.f; }
    if (i < BATCH + 1) solved[i] = 0;   // solved[BATCH] = nsolved counter
}

// ---------------------------------------------------------------------------
// Th/Tl = B-fragment-swizzled split-f16 of Minv (col=n in 1024, k in 1024).
// ---------------------------------------------------------------------------
__global__ __launch_bounds__(256) void split_minv(const float* __restrict__ Minv,
                                                  _Float16* __restrict__ Th,
                                                  _Float16* __restrict__ Tl) {
    int g = blockIdx.x * 256 + threadIdx.x;   // 131072 threads
    int n = g & 1023, k0 = (g >> 10) << 3;
    half8 h, l;
    #pragma unroll
    for (int e = 0; e < 8; ++e) {
        float val = Minv[(size_t)(k0 + e) * MOUT + n];
        _Float16 hh = (_Float16)val;
        h[e] = hh;
        l[e] = (_Float16)(val - (float)hh);
    }
    size_t off = swz(n, k0);
    *(half8*)&Th[off] = h;
    *(half8*)&Tl[off] = l;
}

// ---------------------------------------------------------------------------
// wsh/wsl = B-fragment-swizzled split-f16 of weight (col=n in 512, k in 1024).
// ---------------------------------------------------------------------------
__global__ __launch_bounds__(256) void split_w(const float* __restrict__ w,
                                               _Float16* __restrict__ wsh,
                                               _Float16* __restrict__ wsl) {
    int g = blockIdx.x * 256 + threadIdx.x;   // 65536 threads
    int n = g & 511, k0 = (g >> 9) << 3;
    half8 h, l;
    #pragma unroll
    for (int e = 0; e < 8; ++e) {
        float val = w[(size_t)(k0 + e) * NIN + n];
        _Float16 hh = (_Float16)val;
        h[e] = hh;
        l[e] = (_Float16)(val - (float)hh);
    }
    size_t off = swz(n, k0);
    *(half8*)&wsh[off] = h;
    *(half8*)&wsl[off] = l;
}

// ---------------------------------------------------------------------------
// adb = x @ w^T (fp32, once). Epilogue emits beff = adb as A-swizzled h/l.
// ---------------------------------------------------------------------------
__global__ __launch_bounds__(256) void gemm_adb(const float* __restrict__ x,
                                                const float* __restrict__ w,
                                                float* __restrict__ adb,
                                                _Float16* __restrict__ bh,
                                                _Float16* __restrict__ bl) {
    __shared__ float As[16][68];
    __shared__ float Bs[16][68];
    const int tid = threadIdx.x;
    const int i0 = (blockIdx.x >> 4) * 64, j0 = (blockIdx.x & 15) * 64;
    const int tx = tid & 15, ty = tid >> 4;
    const int lr = tid >> 2, lk = (tid & 3) << 2;
    float acc[4][4] = {};
    for (int k0 = 0; k0 < NIN; k0 += 16) {
        float4 a4 = *(const float4*)&x[(i0 + lr) * NIN + k0 + lk];
        As[lk + 0][lr] = a4.x; As[lk + 1][lr] = a4.y;
        As[lk + 2][lr] = a4.z; As[lk + 3][lr] = a4.w;
        float4 b4 = *(const float4*)&w[(j0 + lr) * NIN + k0 + lk];
        Bs[lk + 0][lr] = b4.x; Bs[lk + 1][lr] = b4.y;
        Bs[lk + 2][lr] = b4.z; Bs[lk + 3][lr] = b4.w;
        __syncthreads();
        #pragma unroll
        for (int kk = 0; kk < 16; ++kk) {
            float4 a_ = *(const float4*)&As[kk][ty << 2];
            float4 b_ = *(const float4*)&Bs[kk][tx << 2];
            #pragma unroll
            for (int r = 0; r < 4; ++r) {
                float av = r == 0 ? a_.x : r == 1 ? a_.y : r == 2 ? a_.z : a_.w;
                acc[r][0] = fmaf(av, b_.x, acc[r][0]);
                acc[r][1] = fmaf(av, b_.y, acc[r][1]);
                acc[r][2] = fmaf(av, b_.z, acc[r][2]);
                acc[r][3] = fmaf(av, b_.w, acc[r][3]);
            }
        }
        __syncthreads();
    }
    const int k4 = j0 + (tx << 2);
    #pragma unroll
    for (int r = 0; r < 4; ++r) {
        const int row = i0 + (ty << 2) + r;
        *(float4*)&adb[(size_t)row * MOUT + k4] =
            make_float4(acc[r][0], acc[r][1], acc[r][2], acc[r][3]);
        half4 h, l;
        #pragma unroll
        for (int e = 0; e < 4; ++e) {
            _Float16 hh = (_Float16)acc[r][e];
            h[e] = hh;
            l[e] = (_Float16)(acc[r][e] - (float)hh);
        }
        size_t off = swz(row, k4);
        *(half4*)&bh[off] = h;
        *(half4*)&bl[off] = l;
    }
}

// ---------------------------------------------------------------------------
// FUSED persistent ADMM loop (cooperative launch, 512 blocks x 256 = 2 blk/CU).
// Per iteration: gemm phase (identical to old gemm_xk) -> grid.sync ->
// update phase (2 rows/block, waves 0-1; identical math to old update) ->
// grid.sync -> global early-exit when all BATCH rows frozen.
// solved[BATCH] doubles as the nsolved counter.
// ---------------------------------------------------------------------------
__global__ __launch_bounds__(256, 2)
void admm_loop(const float* __restrict__ adb, float* __restrict__ xkp,
               float* __restrict__ tbuf,
               _Float16* __restrict__ bh, _Float16* __restrict__ bl,
               const _Float16* __restrict__ Th, const _Float16* __restrict__ Tl,
               float* __restrict__ enc, _Float16* __restrict__ ench,
               _Float16* __restrict__ encl, int* __restrict__ solved) {
    cg::grid_group grid = cg::this_grid();
    const int bid = blockIdx.x;
    const int tid = threadIdx.x, lane = tid & 63;
    int* nsolved = solved + BATCH;

    // gemm-phase geometry
    const int c = bid & 1, tt = bid >> 1;
    const int mt = tt >> 4, nt = tt & 15;
    const int m0 = mt << 6, n0 = nt << 6;
    const int wv = tid >> 6;
    const int wm = (wv >> 1) & 1, wn = wv & 1;
    const int kf0 = c << 4;                // first k32-chunk of this K-half
    // wave wv stages array wv: 0=Ah(bh) 1=Al(bl) 2=Bh(Th) 3=Bl(Tl)
    const _Float16* sarr = (wv == 0) ? bh : (wv == 1) ? bl : (wv == 2) ? Th : Tl;
    const int stile = (wv < 2) ? (mt << 2) : (nt << 2);

    __shared__ _Float16 Ash[16 * 512];     // 16 KB

    // update-phase geometry: 2 rows per block, waves 0-1
    const int urow = (bid << 1) + wv;

    for (int it = 0; it < MAX_ITERS; ++it) {
        // ================= GEMM phase =================
        bool done = ((volatile const int*)solved)[m0 + lane] != 0;
        if (__ballot(done) != ~0ull) {     // block-uniform skip
            floatx4 acc[2][2] = {};
            for (int s = 0; s < 16; ++s) {
                #pragma unroll
                for (int i = 0; i < 4; ++i) {
                    const _Float16* src = sarr +
                        ((((size_t)(stile + i) * 32 + kf0 + s) << 9) +
                         ((size_t)lane << 3));
                    __builtin_amdgcn_global_load_lds(
                        (const __attribute__((address_space(1))) void*)src,
                        (__attribute__((address_space(3))) void*)
                            &Ash[(((wv << 2) + i) << 9)],
                        16, 0, 0);
                }
                __syncthreads();

                half8 ah[2], al[2], bhf[2], blf[2];
                #pragma unroll
                for (int i = 0; i < 2; ++i) {
                    const int at = (wm << 1) + i;
                    ah[i]  = *(const half8*)&Ash[((0 << 11) + (at << 9)) + (lane << 3)];
                    al[i]  = *(const half8*)&Ash[((1 << 11) + (at << 9)) + (lane << 3)];
                    const int bt = (wn << 1) + i;
                    bhf[i] = *(const half8*)&Ash[((2 << 11) + (bt << 9)) + (lane << 3)];
                    blf[i] = *(const half8*)&Ash[((3 << 11) + (bt << 9)) + (lane << 3)];
                }
                #pragma unroll
                for (int i = 0; i < 2; ++i)
                    #pragma unroll
                    for (int j = 0; j < 2; ++j) {
                        acc[i][j] = __builtin_amdgcn_mfma_f32_16x16x32_f16(
                            ah[i], blf[j], acc[i][j], 0, 0, 0);
                        acc[i][j] = __builtin_amdgcn_mfma_f32_16x16x32_f16(
                            al[i], bhf[j], acc[i][j], 0, 0, 0);
                        acc[i][j] = __builtin_amdgcn_mfma_f32_16x16x32_f16(
                            ah[i], bhf[j], acc[i][j], 0, 0, 0);
                    }
                __syncthreads();
            }
            // C/D: col = lane&15, row = (lane>>4)*4 + reg  [m89 verified]
            float* op = xkp + (size_t)c * MM;
            const int orow = (lane >> 4) << 2;
            #pragma unroll
            for (int i = 0; i < 2; ++i) {
                const int gr = m0 + (wm << 5) + (i << 4) + orow;
                #pragma unroll
                for (int j = 0; j < 2; ++j) {
                    const int gc = n0 + (wn << 5) + (j << 4) + (lane & 15);
                    #pragma unroll
                    for (int r = 0; r < 4; ++r)
                        op[(size_t)(gr + r) * MOUT + gc] = acc[i][j][r];
                }
            }
        }
        __threadfence();
        grid.sync();

        // ================= update phase =================
        if (wv < 2 && !((volatile const int*)solved)[urow]) {
            const int row = urow;
            float vn[16];
            float dx2 = 0.f, x2 = 0.f;
            #pragma unroll
            for (int cch = 0; cch < 4; ++cch) {
                const int k4 = (cch << 8) + (lane << 2);
                const size_t j = ((size_t)row << 10) + k4;
                float4 p0 = *(const float4*)&xkp[j];
                float4 p1 = *(const float4*)&xkp[(size_t)MM + j];
                float4 tp = *(const float4*)&tbuf[j];
                float4 aa = *(const float4*)&adb[j];
                float kxa[4] = {p0.x + p1.x, p0.y + p1.y, p0.z + p1.z, p0.w + p1.w};
                float tpa[4] = {tp.x, tp.y, tp.z, tp.w};
                float aaa[4] = {aa.x, aa.y, aa.z, aa.w};
                float tna[4];
                half4 h, l;
                #pragma unroll
                for (int e = 0; e < 4; ++e) {
                    float vprev = shrinkf(tpa[e]);
                    float uu = tpa[e] - vprev;
                    float tn = kxa[e] + uu;          // = u + xk  (ref order)
                    float vv = shrinkf(tn);
                    float un = tn - vv;              // u_new = (u + xk) - v_new
                    float d = vv - vprev;
                    dx2 += d * d;
                    x2 += vv * vv;
                    vn[(cch << 2) + e] = vv;
                    tna[e] = tn;
                    float nb = (aaa[e] + vv) - un;   // (adb + v_new) - u_new
                    _Float16 hh = (_Float16)nb;
                    h[e] = hh;
                    l[e] = (_Float16)(nb - (float)hh);
                }
                *(float4*)&tbuf[j] = make_float4(tna[0], tna[1], tna[2], tna[3]);
                size_t off = swz(row, k4);
                *(half4*)&bh[off] = h;
                *(half4*)&bl[off] = l;
            }
            #pragma unroll
            for (int off = 32; off; off >>= 1) {
                dx2 += __shfl_xor(dx2, off);
                x2  += __shfl_xor(x2, off);
            }
            if (dx2 < TOLF * TOLF * x2) {   // x2==0 -> false (NaN semantics)
                #pragma unroll
                for (int cch = 0; cch < 4; ++cch) {
                    const int k4 = (cch << 8) + (lane << 2);
                    const size_t j = ((size_t)row << 10) + k4;
                    float va[4] = {vn[(cch << 2) + 0], vn[(cch << 2) + 1],
                                   vn[(cch << 2) + 2], vn[(cch << 2) + 3]};
                    *(float4*)&enc[j] = make_float4(va[0], va[1], va[2], va[3]);
                    half4 h, l;
                    #pragma unroll
                    for (int e = 0; e < 4; ++e) {
                        _Float16 hh = (_Float16)va[e];
                        h[e] = hh;
                        l[e] = (_Float16)(va[e] - (float)hh);
                    }
                    size_t off = swz(row, k4);
                    *(half4*)&ench[off] = h;
                    *(half4*)&encl[off] = l;
                }
                if (lane == 0) {
                    solved[row] = 1;
                    atomicAdd(nsolved, 1);   // device-scope
                }
            }
        }
        __threadfence();
        grid.sync();
        if (((volatile const int*)nsolved)[0] == BATCH) break;   // exact early exit
    }
}

// ---------------------------------------------------------------------------
// Fallback (non-cooperative) iteration kernels — identical to previous version.
// ---------------------------------------------------------------------------
__global__ __launch_bounds__(256, 2)
void gemm_xk(const _Float16* __restrict__ bh, const _Float16* __restrict__ bl,
             const _Float16* __restrict__ Th, const _Float16* __restrict__ Tl,
             float* __restrict__ xkp, const int* __restrict__ solved) {
    const int bid = blockIdx.x;
    const int c = bid & 1, t = bid >> 1;
    const int mt = t >> 4, nt = t & 15;
    const int m0 = mt << 6, n0 = nt << 6;
    const int tid = threadIdx.x, lane = tid & 63;

    bool done = ((volatile const int*)solved)[m0 + lane] != 0;
    if (__ballot(done) == ~0ull) return;

    __shared__ _Float16 Ash[16 * 512];

    const int wv = tid >> 6;
    const int wm = (wv >> 1) & 1, wn = wv & 1;
    const int kf0 = c << 4;

    const _Float16* sarr = (wv == 0) ? bh : (wv == 1) ? bl : (wv == 2) ? Th : Tl;
    const int stile = (wv < 2) ? (mt << 2) : (nt << 2);

    floatx4 acc[2][2] = {};
    for (int s = 0; s < 16; ++s) {
        #pragma unroll
        for (int i = 0; i < 4; ++i) {
            const _Float16* src = sarr +
                ((((size_t)(stile + i) * 32 + kf0 + s) << 9) + ((size_t)lane << 3));
            __builtin_amdgcn_global_load_lds(
                (const __attribute__((address_space(1))) void*)src,
                (__attribute__((address_space(3))) void*)
                    &Ash[(((wv << 2) + i) << 9)],
                16, 0, 0);
        }
        __syncthreads();

        half8 ah[2], al[2], bhf[2], blf[2];
        #pragma unroll
        for (int i = 0; i < 2; ++i) {
            const int at = (wm << 1) + i;
            ah[i]  = *(const half8*)&Ash[((0 << 11) + (at << 9)) + (lane << 3)];
            al[i]  = *(const half8*)&Ash[((1 << 11) + (at << 9)) + (lane << 3)];
            const int bt = (wn << 1) + i;
            bhf[i] = *(const half8*)&Ash[((2 << 11) + (bt << 9)) + (lane << 3)];
            blf[i] = *(const half8*)&Ash[((3 << 11) + (bt << 9)) + (lane << 3)];
        }
        #pragma unroll
        for (int i = 0; i < 2; ++i)
            #pragma unroll
            for (int j = 0; j < 2; ++j) {
                acc[i][j] = __builtin_amdgcn_mfma_f32_16x16x32_f16(
                    ah[i], blf[j], acc[i][j], 0, 0, 0);
                acc[i][j] = __builtin_amdgcn_mfma_f32_16x16x32_f16(
                    al[i], bhf[j], acc[i][j], 0, 0, 0);
                acc[i][j] = __builtin_amdgcn_mfma_f32_16x16x32_f16(
                    ah[i], bhf[j], acc[i][j], 0, 0, 0);
            }
        __syncthreads();
    }

    float* op = xkp + (size_t)c * MM;
    const int orow = (lane >> 4) << 2;
    #pragma unroll
    for (int i = 0; i < 2; ++i) {
        const int gr = m0 + (wm << 5) + (i << 4) + orow;
        #pragma unroll
        for (int j = 0; j < 2; ++j) {
            const int gc = n0 + (wn << 5) + (j << 4) + (lane & 15);
            #pragma unroll
            for (int r = 0; r < 4; ++r)
                op[(size_t)(gr + r) * MOUT + gc] = acc[i][j][r];
        }
    }
}

__global__ __launch_bounds__(256) void update(const float* __restrict__ adb,
                                              const float* __restrict__ xkp,
                                              float* __restrict__ t,
                                              _Float16* __restrict__ bh,
                                              _Float16* __restrict__ bl,
                                              float* __restrict__ enc,
                                              _Float16* __restrict__ ench,
                                              _Float16* __restrict__ encl,
                                              int* solved) {
    const int tid = threadIdx.x, lane = tid & 63;
    const int row = (blockIdx.x << 2) + (tid >> 6);
    if (((volatile const int*)solved)[row]) return;

    float vn[16];
    float dx2 = 0.f, x2 = 0.f;
    #pragma unroll
    for (int cch = 0; cch < 4; ++cch) {
        const int k4 = (cch << 8) + (lane << 2);
        const size_t j = ((size_t)row << 10) + k4;
        float4 p0 = *(const float4*)&xkp[j];
        float4 p1 = *(const float4*)&xkp[(size_t)MM + j];
        float4 tp = *(const float4*)&t[j];
        float4 aa = *(const float4*)&adb[j];
        float kxa[4] = {p0.x + p1.x, p0.y + p1.y, p0.z + p1.z, p0.w + p1.w};
        float tpa[4] = {tp.x, tp.y, tp.z, tp.w};
        float aaa[4] = {aa.x, aa.y, aa.z, aa.w};
        float tna[4];
        half4 h, l;
        #pragma unroll
        for (int e = 0; e < 4; ++e) {
            float vprev = shrinkf(tpa[e]);
            float uu = tpa[e] - vprev;
            float tn = kxa[e] + uu;
            float vv = shrinkf(tn);
            float un = tn - vv;
            float d = vv - vprev;
            dx2 += d * d;
            x2 += vv * vv;
            vn[(cch << 2) + e] = vv;
            tna[e] = tn;
            float nb = (aaa[e] + vv) - un;
            _Float16 hh = (_Float16)nb;
            h[e] = hh;
            l[e] = (_Float16)(nb - (float)hh);
        }
        *(float4*)&t[j] = make_float4(tna[0], tna[1], tna[2], tna[3]);
        size_t off = swz(row, k4);
        *(half4*)&bh[off] = h;
        *(half4*)&bl[off] = l;
    }
    #pragma unroll
    for (int off = 32; off; off >>= 1) {
        dx2 += __shfl_xor(dx2, off);
        x2  += __shfl_xor(x2, off);
    }
    if (dx2 < TOLF * TOLF * x2) {
        #pragma unroll
        for (int cch = 0; cch < 4; ++cch) {
            const int k4 = (cch << 8) + (lane << 2);
            const size_t j = ((size_t)row << 10) + k4;
            float va[4] = {vn[(cch << 2) + 0], vn[(cch << 2) + 1],
                           vn[(cch << 2) + 2], vn[(cch << 2) + 3]};
            *(float4*)&enc[j] = make_float4(va[0], va[1], va[2], va[3]);
            half4 h, l;
            #pragma unroll
            for (int e = 0; e < 4; ++e) {
                _Float16 hh = (_Float16)va[e];
                h[e] = hh;
                l[e] = (_Float16)(va[e] - (float)hh);
            }
            size_t off = swz(row, k4);
            *(half4*)&ench[off] = h;
            *(half4*)&encl[off] = l;
        }
        if (lane == 0) ((volatile int*)solved)[row] = 1;
    }
}

// ---------------------------------------------------------------------------
// dec = enc @ w, split-f16 MFMA, runs ONCE. 128x128 tile, S=8 whole-partition
// A staging (64 KB), one barrier, atomicAdd epilogue (one-time cost).
// ---------------------------------------------------------------------------
__global__ __launch_bounds__(256, 2)
void mfma_dec(const _Float16* __restrict__ Ahg, const _Float16* __restrict__ Alg,
              const _Float16* __restrict__ Bhg, const _Float16* __restrict__ Blg,
              float* __restrict__ out) {
    constexpr int NSTR = NIN;              // 512
    constexpr int NT = NSTR / 128;         // 4
    const int bid = blockIdx.x;
    const int c = bid & 7, t = bid >> 3;
    const int mt = t / NT, nt = t % NT;
    const int tid = threadIdx.x, lane = tid & 63;

    __shared__ _Float16 Ash[64 * 512];     // 64 KB

    const int wv = tid >> 6;
    const int wm = (tid >> 7) & 1, wn = (tid >> 6) & 1;
    const int kf0 = c << 2;

    #pragma unroll
    for (int i = 0; i < 16; ++i) {
        const int chunk = (wv << 4) + i;
        const int rt = chunk >> 3, kc = (chunk >> 1) & 3, hl = chunk & 1;
        const _Float16* src = (hl ? Alg : Ahg) +
            ((((size_t)((mt << 3) + rt) * 32 + kf0 + kc) << 9) + ((size_t)lane << 3));
        __builtin_amdgcn_global_load_lds(
            (const __attribute__((address_space(1))) void*)src,
            (__attribute__((address_space(3))) void*)&Ash[(size_t)chunk << 9],
            16, 0, 0);
    }
    __syncthreads();

    const int ct0 = nt * 8 + (wn << 2);
    const _Float16* pBh = Bhg + ((((size_t)ct0 * 32 + kf0) * 64 + lane) << 3);
    const _Float16* pBl = Blg + ((((size_t)ct0 * 32 + kf0) * 64 + lane) << 3);

    floatx4 acc[4][4] = {};
    #pragma unroll
    for (int s = 0; s < 4; ++s) {
        half8 bhf[4], blf[4];
        #pragma unroll
        for (int j = 0; j < 4; ++j) {
            bhf[j] = *(const half8*)(pBh + ((size_t)j << 14) + ((size_t)s << 9));
            blf[j] = *(const half8*)(pBl + ((size_t)j << 14) + ((size_t)s << 9));
        }
        half8 ah[4], al[4];
        #pragma unroll
        for (int i = 0; i < 4; ++i) {
            const int rt = (wm << 2) + i;
            ah[i] = *(const half8*)&Ash[((((rt << 2) + s) << 1) << 9) + (lane << 3)];
            al[i] = *(const half8*)&Ash[(((((rt << 2) + s) << 1) + 1) << 9) + (lane << 3)];
        }
        #pragma unroll
        for (int i = 0; i < 4; ++i)
            #pragma unroll
            for (int j = 0; j < 4; ++j) {
                acc[i][j] = __builtin_amdgcn_mfma_f32_16x16x32_f16(
                    ah[i], blf[j], acc[i][j], 0, 0, 0);
                acc[i][j] = __builtin_amdgcn_mfma_f32_16x16x32_f16(
                    al[i], bhf[j], acc[i][j], 0, 0, 0);
                acc[i][j] = __builtin_amdgcn_mfma_f32_16x16x32_f16(
                    ah[i], bhf[j], acc[i][j], 0, 0, 0);
            }
    }

    const int orow = (lane >> 4) << 2;
    #pragma unroll
    for (int i = 0; i < 4; ++i) {
        const int gr = (mt << 7) + (wm << 6) + (i << 4) + orow;
        #pragma unroll
        for (int j = 0; j < 4; ++j) {
            const int gc = nt * 128 + (wn << 6) + (j << 4) + (lane & 15);
            #pragma unroll
            for (int r = 0; r < 4; ++r)
                atomicAdd(&out[(size_t)(gr + r) * NSTR + gc], acc[i][j][r]);
        }
    }
}

// ---------------------------------------------------------------------------
extern "C" void kernel_launch(void* const* d_in, const int* in_sizes, int n_in,
                              void* d_out, int out_size, void* d_ws, size_t ws_size,
                              hipStream_t stream) {
    const float* x    = (const float*)d_in[0];
    const float* w    = (const float*)d_in[1];
    const float* Minv = (const float*)d_in[2];

    float* enc = (float*)d_out;          // encoded: 1024*1024
    float* dec = enc + MM;               // decoded: 1024*512

    // ws (floats): adb MM | t MM | xkp 2*MM | halves: bh,bl,Th,Tl,ench,encl MM,
    // wsh,wsl MM/2 | solved[BATCH+1]. ~30 MB.
    float* ws  = (float*)d_ws;
    float* adb = ws;
    float* t   = ws + (size_t)MM;
    float* xkp = ws + 2 * (size_t)MM;

    _Float16* bh   = (_Float16*)(ws + 4 * (size_t)MM);
    _Float16* bl   = bh + (size_t)MM;
    _Float16* Th   = bl + (size_t)MM;
    _Float16* Tl   = Th + (size_t)MM;
    _Float16* ench = Tl + (size_t)MM;
    _Float16* encl = ench + (size_t)MM;
    _Float16* wsh  = encl + (size_t)MM;
    _Float16* wsl  = wsh + (size_t)(NIN * MOUT);
    int* solved    = (int*)(wsl + (size_t)(NIN * MOUT));

    zero_init<<<(MM + 255) / 256, 256, 0, stream>>>(t, enc, dec, (float*)ench,
                                                    (float*)encl, solved);
    split_minv<<<512, 256, 0, stream>>>(Minv, Th, Tl);
    split_w<<<256, 256, 0, stream>>>(w, wsh, wsl);
    gemm_adb<<<256, 256, 0, stream>>>(x, w, adb, bh, bl);

    void* cargs[] = {(void*)&adb, (void*)&xkp, (void*)&t,
                     (void*)&bh,  (void*)&bl,  (void*)&Th, (void*)&Tl,
                     (void*)&enc, (void*)&ench, (void*)&encl, (void*)&solved};
    hipError_t e = hipLaunchCooperativeKernel(
        reinterpret_cast<void*>(admm_loop), dim3(512), dim3(256), cargs, 0, stream);
    if (e != hipSuccess) {
        // fallback: classic 2-kernel iteration loop
        for (int it = 0; it < MAX_ITERS; ++it) {
            gemm_xk<<<512, 256, 0, stream>>>(bh, bl, Th, Tl, xkp, solved);
            update<<<256, 256, 0, stream>>>(adb, xkp, t, bh, bl, enc, ench, encl,
                                            solved);
        }
    }

    mfma_dec<<<256, 256, 0, stream>>>(ench, encl, wsh, wsl, dec);
}

// Round 2
// 10819.636 us; speedup vs baseline: 2.3035x; 2.3035x over previous
//
#include <hip/hip_runtime.h>

typedef _Float16 half8 __attribute__((ext_vector_type(8)));
typedef _Float16 half4 __attribute__((ext_vector_type(4)));
typedef float floatx4 __attribute__((ext_vector_type(4)));

static constexpr int BATCH = 1024;
static constexpr int NIN   = 512;    // in_features
static constexpr int MOUT  = 1024;   // out_features
static constexpr float LAMBD = 0.2f;
static constexpr float TOLF  = 1e-4f;
static constexpr int MAX_ITERS = 100;
static constexpr int MM = BATCH * MOUT;   // 1M elements

// Fragment-swizzled layout for 16x16x32 MFMA operands (A: rows, B: cols), f16:
//   flat = ((tile16*32 + kchunk32)*64 + lane)*8 + elem
//   lane = (idx&15) | (((k>>3)&3)<<4), elem = k&7
__device__ __forceinline__ size_t swz(int idx, int k) {
    return ((((size_t)(idx >> 4) * 32 + (k >> 5)) * 64 +
             ((idx & 15) | (((k >> 3) & 3) << 4))) << 3) + (k & 7);
}

__device__ __forceinline__ float shrinkf(float t) {
    float a = fabsf(t) - LAMBD;
    return a > 0.f ? copysignf(a, t) : 0.f;
}

// ---------------------------------------------------------------------------
// Per-group barrier (32 blocks/group, 16 independent groups). Monotonic
// generation target avoids sense-reversal races. Release/acquire via
// __threadfence (agent scope: L2 wb + L1/L2 inv) — the same coherence a
// kernel boundary provides, without the ~300us cg::grid.sync cost.
// ---------------------------------------------------------------------------
__device__ __forceinline__ void gbar(int* cnt, int* gen, int nb, int target) {
    __syncthreads();                       // drains vmcnt: block's stores in L2
    if (threadIdx.x == 0) {
        __threadfence();                   // release: wb this XCD's L2
        int old = atomicAdd(cnt, 1);       // device-scope by default
        if (old == nb - 1) {
            __hip_atomic_store(cnt, 0, __ATOMIC_RELAXED, __HIP_MEMORY_SCOPE_AGENT);
            __hip_atomic_store(gen, target, __ATOMIC_RELEASE, __HIP_MEMORY_SCOPE_AGENT);
        } else {
            while (__hip_atomic_load(gen, __ATOMIC_RELAXED,
                                     __HIP_MEMORY_SCOPE_AGENT) < target)
                __builtin_amdgcn_s_sleep(2);
        }
        __threadfence();                   // acquire: inv L1/L2 before reads
    }
    __syncthreads();
}

// ---------------------------------------------------------------------------
// zero-init: t, enc, dec, swizzled enc halves, solved + barrier region
// ---------------------------------------------------------------------------
__global__ __launch_bounds__(256) void zero_init(float* t, float* enc,
                                                 float* dec, float* ench_f,
                                                 float* encl_f, int* solved) {
    int i = blockIdx.x * 256 + threadIdx.x;
    if (i < MM) { t[i] = 0.f; enc[i] = 0.f; }
    if (i < MM / 2) { dec[i] = 0.f; ench_f[i] = 0.f; encl_f[i] = 0.f; }
    if (i < 4096) solved[i] = 0;   // solved[0..1024] + barrier words @ +1088
}

// ---------------------------------------------------------------------------
// Th/Tl = B-fragment-swizzled split-f16 of Minv (col=n in 1024, k in 1024).
// ---------------------------------------------------------------------------
__global__ __launch_bounds__(256) void split_minv(const float* __restrict__ Minv,
                                                  _Float16* __restrict__ Th,
                                                  _Float16* __restrict__ Tl) {
    int g = blockIdx.x * 256 + threadIdx.x;   // 131072 threads
    int n = g & 1023, k0 = (g >> 10) << 3;
    half8 h, l;
    #pragma unroll
    for (int e = 0; e < 8; ++e) {
        float val = Minv[(size_t)(k0 + e) * MOUT + n];
        _Float16 hh = (_Float16)val;
        h[e] = hh;
        l[e] = (_Float16)(val - (float)hh);
    }
    size_t off = swz(n, k0);
    *(half8*)&Th[off] = h;
    *(half8*)&Tl[off] = l;
}

// ---------------------------------------------------------------------------
// wsh/wsl = B-fragment-swizzled split-f16 of weight (col=n in 512, k in 1024).
// ---------------------------------------------------------------------------
__global__ __launch_bounds__(256) void split_w(const float* __restrict__ w,
                                               _Float16* __restrict__ wsh,
                                               _Float16* __restrict__ wsl) {
    int g = blockIdx.x * 256 + threadIdx.x;   // 65536 threads
    int n = g & 511, k0 = (g >> 9) << 3;
    half8 h, l;
    #pragma unroll
    for (int e = 0; e < 8; ++e) {
        float val = w[(size_t)(k0 + e) * NIN + n];
        _Float16 hh = (_Float16)val;
        h[e] = hh;
        l[e] = (_Float16)(val - (float)hh);
    }
    size_t off = swz(n, k0);
    *(half8*)&wsh[off] = h;
    *(half8*)&wsl[off] = l;
}

// ---------------------------------------------------------------------------
// adb = x @ w^T (fp32, once). Epilogue emits beff = adb as A-swizzled h/l.
// ---------------------------------------------------------------------------
__global__ __launch_bounds__(256) void gemm_adb(const float* __restrict__ x,
                                                const float* __restrict__ w,
                                                float* __restrict__ adb,
                                                _Float16* __restrict__ bh,
                                                _Float16* __restrict__ bl) {
    __shared__ float As[16][68];
    __shared__ float Bs[16][68];
    const int tid = threadIdx.x;
    const int i0 = (blockIdx.x >> 4) * 64, j0 = (blockIdx.x & 15) * 64;
    const int tx = tid & 15, ty = tid >> 4;
    const int lr = tid >> 2, lk = (tid & 3) << 2;
    float acc[4][4] = {};
    for (int k0 = 0; k0 < NIN; k0 += 16) {
        float4 a4 = *(const float4*)&x[(i0 + lr) * NIN + k0 + lk];
        As[lk + 0][lr] = a4.x; As[lk + 1][lr] = a4.y;
        As[lk + 2][lr] = a4.z; As[lk + 3][lr] = a4.w;
        float4 b4 = *(const float4*)&w[(j0 + lr) * NIN + k0 + lk];
        Bs[lk + 0][lr] = b4.x; Bs[lk + 1][lr] = b4.y;
        Bs[lk + 2][lr] = b4.z; Bs[lk + 3][lr] = b4.w;
        __syncthreads();
        #pragma unroll
        for (int kk = 0; kk < 16; ++kk) {
            float4 a_ = *(const float4*)&As[kk][ty << 2];
            float4 b_ = *(const float4*)&Bs[kk][tx << 2];
            #pragma unroll
            for (int r = 0; r < 4; ++r) {
                float av = r == 0 ? a_.x : r == 1 ? a_.y : r == 2 ? a_.z : a_.w;
                acc[r][0] = fmaf(av, b_.x, acc[r][0]);
                acc[r][1] = fmaf(av, b_.y, acc[r][1]);
                acc[r][2] = fmaf(av, b_.z, acc[r][2]);
                acc[r][3] = fmaf(av, b_.w, acc[r][3]);
            }
        }
        __syncthreads();
    }
    const int k4 = j0 + (tx << 2);
    #pragma unroll
    for (int r = 0; r < 4; ++r) {
        const int row = i0 + (ty << 2) + r;
        *(float4*)&adb[(size_t)row * MOUT + k4] =
            make_float4(acc[r][0], acc[r][1], acc[r][2], acc[r][3]);
        half4 h, l;
        #pragma unroll
        for (int e = 0; e < 4; ++e) {
            _Float16 hh = (_Float16)acc[r][e];
            h[e] = hh;
            l[e] = (_Float16)(acc[r][e] - (float)hh);
        }
        size_t off = swz(row, k4);
        *(half4*)&bh[off] = h;
        *(half4*)&bl[off] = l;
    }
}

// ---------------------------------------------------------------------------
// FUSED persistent ADMM loop with STRIPE-LOCAL barriers.
// Group = stripe mt = blocks [mt*32 .. mt*32+31] (16 nt x 2 c). The stripe's
// gemm only needs bh/bl rows of stripe mt; updates of those 64 rows live in
// the same 32 blocks (2 rows/block, waves 0-1). Groups are fully independent:
// per-iteration sync is a 32-block barrier, and each stripe exits as soon as
// its own 64 rows are frozen. Cooperative-style co-residency is guaranteed by
// grid=512 <= 2 blk/CU * 256 CU (launch_bounds(256,2), 16 KB LDS, 68 VGPR).
// ---------------------------------------------------------------------------
__global__ __launch_bounds__(256, 2)
void admm_loop(const float* __restrict__ adb, float* __restrict__ xkp,
               float* __restrict__ tbuf,
               _Float16* __restrict__ bh, _Float16* __restrict__ bl,
               const _Float16* __restrict__ Th, const _Float16* __restrict__ Tl,
               float* __restrict__ enc, _Float16* __restrict__ ench,
               _Float16* __restrict__ encl, int* __restrict__ solved,
               int* __restrict__ bar) {
    const int bid = blockIdx.x;
    const int tid = threadIdx.x, lane = tid & 63;

    // gemm-phase geometry (same mapping as before: mt = bid>>5)
    const int c = bid & 1;
    const int nt = (bid >> 1) & 15;
    const int mt = bid >> 5;
    const int m0 = mt << 6, n0 = nt << 6;
    const int wv = tid >> 6;
    const int wm = (wv >> 1) & 1, wn = wv & 1;
    const int kf0 = c << 4;                // first k32-chunk of this K-half
    // wave wv stages array wv: 0=Ah(bh) 1=Al(bl) 2=Bh(Th) 3=Bl(Tl)
    const _Float16* sarr = (wv == 0) ? bh : (wv == 1) ? bl : (wv == 2) ? Th : Tl;
    const int stile = (wv < 2) ? (mt << 2) : (nt << 2);

    __shared__ _Float16 Ash[16 * 512];     // 16 KB

    // per-group barrier words (128 B apart per group)
    int* gcnt = bar + (mt << 5);
    int* ggen = bar + (mt << 5) + 16;

    // update-phase: 2 rows per block (waves 0-1), covering stripe mt
    const int urow = m0 + ((bid & 31) << 1) + wv;

    for (int it = 0; it < MAX_ITERS; ++it) {
        // ================= GEMM phase =================
        floatx4 acc[2][2] = {};
        for (int s = 0; s < 16; ++s) {
            #pragma unroll
            for (int i = 0; i < 4; ++i) {
                const _Float16* src = sarr +
                    ((((size_t)(stile + i) * 32 + kf0 + s) << 9) +
                     ((size_t)lane << 3));
                __builtin_amdgcn_global_load_lds(
                    (const __attribute__((address_space(1))) void*)src,
                    (__attribute__((address_space(3))) void*)
                        &Ash[(((wv << 2) + i) << 9)],
                    16, 0, 0);
            }
            __syncthreads();

            half8 ah[2], al[2], bhf[2], blf[2];
            #pragma unroll
            for (int i = 0; i < 2; ++i) {
                const int at = (wm << 1) + i;
                ah[i]  = *(const half8*)&Ash[((0 << 11) + (at << 9)) + (lane << 3)];
                al[i]  = *(const half8*)&Ash[((1 << 11) + (at << 9)) + (lane << 3)];
                const int bt = (wn << 1) + i;
                bhf[i] = *(const half8*)&Ash[((2 << 11) + (bt << 9)) + (lane << 3)];
                blf[i] = *(const half8*)&Ash[((3 << 11) + (bt << 9)) + (lane << 3)];
            }
            #pragma unroll
            for (int i = 0; i < 2; ++i)
                #pragma unroll
                for (int j = 0; j < 2; ++j) {
                    acc[i][j] = __builtin_amdgcn_mfma_f32_16x16x32_f16(
                        ah[i], blf[j], acc[i][j], 0, 0, 0);
                    acc[i][j] = __builtin_amdgcn_mfma_f32_16x16x32_f16(
                        al[i], bhf[j], acc[i][j], 0, 0, 0);
                    acc[i][j] = __builtin_amdgcn_mfma_f32_16x16x32_f16(
                        ah[i], bhf[j], acc[i][j], 0, 0, 0);
                }
            __syncthreads();
        }
        // C/D: col = lane&15, row = (lane>>4)*4 + reg  [m89 verified]
        {
            float* op = xkp + (size_t)c * MM;
            const int orow = (lane >> 4) << 2;
            #pragma unroll
            for (int i = 0; i < 2; ++i) {
                const int gr = m0 + (wm << 5) + (i << 4) + orow;
                #pragma unroll
                for (int j = 0; j < 2; ++j) {
                    const int gc = n0 + (wn << 5) + (j << 4) + (lane & 15);
                    #pragma unroll
                    for (int r = 0; r < 4; ++r)
                        op[(size_t)(gr + r) * MOUT + gc] = acc[i][j][r];
                }
            }
        }
        gbar(gcnt, ggen, 32, 2 * it + 1);

        // ================= update phase =================
        if (wv < 2 && !((volatile const int*)solved)[urow]) {
            const int row = urow;
            float vn[16];
            float dx2 = 0.f, x2 = 0.f;
            #pragma unroll
            for (int cch = 0; cch < 4; ++cch) {
                const int k4 = (cch << 8) + (lane << 2);
                const size_t j = ((size_t)row << 10) + k4;
                float4 p0 = *(const float4*)&xkp[j];
                float4 p1 = *(const float4*)&xkp[(size_t)MM + j];
                float4 tp = *(const float4*)&tbuf[j];
                float4 aa = *(const float4*)&adb[j];
                float kxa[4] = {p0.x + p1.x, p0.y + p1.y, p0.z + p1.z, p0.w + p1.w};
                float tpa[4] = {tp.x, tp.y, tp.z, tp.w};
                float aaa[4] = {aa.x, aa.y, aa.z, aa.w};
                float tna[4];
                half4 h, l;
                #pragma unroll
                for (int e = 0; e < 4; ++e) {
                    float vprev = shrinkf(tpa[e]);
                    float uu = tpa[e] - vprev;
                    float tn = kxa[e] + uu;          // = u + xk  (ref order)
                    float vv = shrinkf(tn);
                    float un = tn - vv;              // u_new = (u + xk) - v_new
                    float d = vv - vprev;
                    dx2 += d * d;
                    x2 += vv * vv;
                    vn[(cch << 2) + e] = vv;
                    tna[e] = tn;
                    float nb = (aaa[e] + vv) - un;   // (adb + v_new) - u_new
                    _Float16 hh = (_Float16)nb;
                    h[e] = hh;
                    l[e] = (_Float16)(nb - (float)hh);
                }
                *(float4*)&tbuf[j] = make_float4(tna[0], tna[1], tna[2], tna[3]);
                size_t off = swz(row, k4);
                *(half4*)&bh[off] = h;
                *(half4*)&bl[off] = l;
            }
            #pragma unroll
            for (int off = 32; off; off >>= 1) {
                dx2 += __shfl_xor(dx2, off);
                x2  += __shfl_xor(x2, off);
            }
            if (dx2 < TOLF * TOLF * x2) {   // x2==0 -> false (NaN semantics)
                #pragma unroll
                for (int cch = 0; cch < 4; ++cch) {
                    const int k4 = (cch << 8) + (lane << 2);
                    const size_t j = ((size_t)row << 10) + k4;
                    float va[4] = {vn[(cch << 2) + 0], vn[(cch << 2) + 1],
                                   vn[(cch << 2) + 2], vn[(cch << 2) + 3]};
                    *(float4*)&enc[j] = make_float4(va[0], va[1], va[2], va[3]);
                    half4 h, l;
                    #pragma unroll
                    for (int e = 0; e < 4; ++e) {
                        _Float16 hh = (_Float16)va[e];
                        h[e] = hh;
                        l[e] = (_Float16)(va[e] - (float)hh);
                    }
                    size_t off = swz(row, k4);
                    *(half4*)&ench[off] = h;
                    *(half4*)&encl[off] = l;
                }
                if (lane == 0) ((volatile int*)solved)[row] = 1;
            }
        }
        gbar(gcnt, ggen, 32, 2 * it + 2);

        // stripe-local exact early exit (group-uniform decision)
        if (__ballot(((volatile const int*)solved)[m0 + lane] != 0) == ~0ull)
            break;
    }
}

// ---------------------------------------------------------------------------
// Fallback (non-persistent) iteration kernels — proven baseline path.
// ---------------------------------------------------------------------------
__global__ __launch_bounds__(256, 2)
void gemm_xk(const _Float16* __restrict__ bh, const _Float16* __restrict__ bl,
             const _Float16* __restrict__ Th, const _Float16* __restrict__ Tl,
             float* __restrict__ xkp, const int* __restrict__ solved) {
    const int bid = blockIdx.x;
    const int c = bid & 1, t = bid >> 1;
    const int mt = t >> 4, nt = t & 15;
    const int m0 = mt << 6, n0 = nt << 6;
    const int tid = threadIdx.x, lane = tid & 63;

    bool done = ((volatile const int*)solved)[m0 + lane] != 0;
    if (__ballot(done) == ~0ull) return;

    __shared__ _Float16 Ash[16 * 512];

    const int wv = tid >> 6;
    const int wm = (wv >> 1) & 1, wn = wv & 1;
    const int kf0 = c << 4;

    const _Float16* sarr = (wv == 0) ? bh : (wv == 1) ? bl : (wv == 2) ? Th : Tl;
    const int stile = (wv < 2) ? (mt << 2) : (nt << 2);

    floatx4 acc[2][2] = {};
    for (int s = 0; s < 16; ++s) {
        #pragma unroll
        for (int i = 0; i < 4; ++i) {
            const _Float16* src = sarr +
                ((((size_t)(stile + i) * 32 + kf0 + s) << 9) + ((size_t)lane << 3));
            __builtin_amdgcn_global_load_lds(
                (const __attribute__((address_space(1))) void*)src,
                (__attribute__((address_space(3))) void*)
                    &Ash[(((wv << 2) + i) << 9)],
                16, 0, 0);
        }
        __syncthreads();

        half8 ah[2], al[2], bhf[2], blf[2];
        #pragma unroll
        for (int i = 0; i < 2; ++i) {
            const int at = (wm << 1) + i;
            ah[i]  = *(const half8*)&Ash[((0 << 11) + (at << 9)) + (lane << 3)];
            al[i]  = *(const half8*)&Ash[((1 << 11) + (at << 9)) + (lane << 3)];
            const int bt = (wn << 1) + i;
            bhf[i] = *(const half8*)&Ash[((2 << 11) + (bt << 9)) + (lane << 3)];
            blf[i] = *(const half8*)&Ash[((3 << 11) + (bt << 9)) + (lane << 3)];
        }
        #pragma unroll
        for (int i = 0; i < 2; ++i)
            #pragma unroll
            for (int j = 0; j < 2; ++j) {
                acc[i][j] = __builtin_amdgcn_mfma_f32_16x16x32_f16(
                    ah[i], blf[j], acc[i][j], 0, 0, 0);
                acc[i][j] = __builtin_amdgcn_mfma_f32_16x16x32_f16(
                    al[i], bhf[j], acc[i][j], 0, 0, 0);
                acc[i][j] = __builtin_amdgcn_mfma_f32_16x16x32_f16(
                    ah[i], bhf[j], acc[i][j], 0, 0, 0);
            }
        __syncthreads();
    }

    float* op = xkp + (size_t)c * MM;
    const int orow = (lane >> 4) << 2;
    #pragma unroll
    for (int i = 0; i < 2; ++i) {
        const int gr = m0 + (wm << 5) + (i << 4) + orow;
        #pragma unroll
        for (int j = 0; j < 2; ++j) {
            const int gc = n0 + (wn << 5) + (j << 4) + (lane & 15);
            #pragma unroll
            for (int r = 0; r < 4; ++r)
                op[(size_t)(gr + r) * MOUT + gc] = acc[i][j][r];
        }
    }
}

__global__ __launch_bounds__(256) void update(const float* __restrict__ adb,
                                              const float* __restrict__ xkp,
                                              float* __restrict__ t,
                                              _Float16* __restrict__ bh,
                                              _Float16* __restrict__ bl,
                                              float* __restrict__ enc,
                                              _Float16* __restrict__ ench,
                                              _Float16* __restrict__ encl,
                                              int* solved) {
    const int tid = threadIdx.x, lane = tid & 63;
    const int row = (blockIdx.x << 2) + (tid >> 6);
    if (((volatile const int*)solved)[row]) return;

    float vn[16];
    float dx2 = 0.f, x2 = 0.f;
    #pragma unroll
    for (int cch = 0; cch < 4; ++cch) {
        const int k4 = (cch << 8) + (lane << 2);
        const size_t j = ((size_t)row << 10) + k4;
        float4 p0 = *(const float4*)&xkp[j];
        float4 p1 = *(const float4*)&xkp[(size_t)MM + j];
        float4 tp = *(const float4*)&t[j];
        float4 aa = *(const float4*)&adb[j];
        float kxa[4] = {p0.x + p1.x, p0.y + p1.y, p0.z + p1.z, p0.w + p1.w};
        float tpa[4] = {tp.x, tp.y, tp.z, tp.w};
        float aaa[4] = {aa.x, aa.y, aa.z, aa.w};
        float tna[4];
        half4 h, l;
        #pragma unroll
        for (int e = 0; e < 4; ++e) {
            float vprev = shrinkf(tpa[e]);
            float uu = tpa[e] - vprev;
            float tn = kxa[e] + uu;
            float vv = shrinkf(tn);
            float un = tn - vv;
            float d = vv - vprev;
            dx2 += d * d;
            x2 += vv * vv;
            vn[(cch << 2) + e] = vv;
            tna[e] = tn;
            float nb = (aaa[e] + vv) - un;
            _Float16 hh = (_Float16)nb;
            h[e] = hh;
            l[e] = (_Float16)(nb - (float)hh);
        }
        *(float4*)&t[j] = make_float4(tna[0], tna[1], tna[2], tna[3]);
        size_t off = swz(row, k4);
        *(half4*)&bh[off] = h;
        *(half4*)&bl[off] = l;
    }
    #pragma unroll
    for (int off = 32; off; off >>= 1) {
        dx2 += __shfl_xor(dx2, off);
        x2  += __shfl_xor(x2, off);
    }
    if (dx2 < TOLF * TOLF * x2) {
        #pragma unroll
        for (int cch = 0; cch < 4; ++cch) {
            const int k4 = (cch << 8) + (lane << 2);
            const size_t j = ((size_t)row << 10) + k4;
            float va[4] = {vn[(cch << 2) + 0], vn[(cch << 2) + 1],
                           vn[(cch << 2) + 2], vn[(cch << 2) + 3]};
            *(float4*)&enc[j] = make_float4(va[0], va[1], va[2], va[3]);
            half4 h, l;
            #pragma unroll
            for (int e = 0; e < 4; ++e) {
                _Float16 hh = (_Float16)va[e];
                h[e] = hh;
                l[e] = (_Float16)(va[e] - (float)hh);
            }
            size_t off = swz(row, k4);
            *(half4*)&ench[off] = h;
            *(half4*)&encl[off] = l;
        }
        if (lane == 0) ((volatile int*)solved)[row] = 1;
    }
}

// ---------------------------------------------------------------------------
// dec = enc @ w, split-f16 MFMA, runs ONCE. 128x128 tile, S=8 whole-partition
// A staging (64 KB), one barrier, atomicAdd epilogue (one-time cost).
// ---------------------------------------------------------------------------
__global__ __launch_bounds__(256, 2)
void mfma_dec(const _Float16* __restrict__ Ahg, const _Float16* __restrict__ Alg,
              const _Float16* __restrict__ Bhg, const _Float16* __restrict__ Blg,
              float* __restrict__ out) {
    constexpr int NSTR = NIN;              // 512
    constexpr int NT = NSTR / 128;         // 4
    const int bid = blockIdx.x;
    const int c = bid & 7, t = bid >> 3;
    const int mt = t / NT, nt = t % NT;
    const int tid = threadIdx.x, lane = tid & 63;

    __shared__ _Float16 Ash[64 * 512];     // 64 KB

    const int wv = tid >> 6;
    const int wm = (tid >> 7) & 1, wn = (tid >> 6) & 1;
    const int kf0 = c << 2;

    #pragma unroll
    for (int i = 0; i < 16; ++i) {
        const int chunk = (wv << 4) + i;
        const int rt = chunk >> 3, kc = (chunk >> 1) & 3, hl = chunk & 1;
        const _Float16* src = (hl ? Alg : Ahg) +
            ((((size_t)((mt << 3) + rt) * 32 + kf0 + kc) << 9) + ((size_t)lane << 3));
        __builtin_amdgcn_global_load_lds(
            (const __attribute__((address_space(1))) void*)src,
            (__attribute__((address_space(3))) void*)&Ash[(size_t)chunk << 9],
            16, 0, 0);
    }
    __syncthreads();

    const int ct0 = nt * 8 + (wn << 2);
    const _Float16* pBh = Bhg + ((((size_t)ct0 * 32 + kf0) * 64 + lane) << 3);
    const _Float16* pBl = Blg + ((((size_t)ct0 * 32 + kf0) * 64 + lane) << 3);

    floatx4 acc[4][4] = {};
    #pragma unroll
    for (int s = 0; s < 4; ++s) {
        half8 bhf[4], blf[4];
        #pragma unroll
        for (int j = 0; j < 4; ++j) {
            bhf[j] = *(const half8*)(pBh + ((size_t)j << 14) + ((size_t)s << 9));
            blf[j] = *(const half8*)(pBl + ((size_t)j << 14) + ((size_t)s << 9));
        }
        half8 ah[4], al[4];
        #pragma unroll
        for (int i = 0; i < 4; ++i) {
            const int rt = (wm << 2) + i;
            ah[i] = *(const half8*)&Ash[((((rt << 2) + s) << 1) << 9) + (lane << 3)];
            al[i] = *(const half8*)&Ash[(((((rt << 2) + s) << 1) + 1) << 9) + (lane << 3)];
        }
        #pragma unroll
        for (int i = 0; i < 4; ++i)
            #pragma unroll
            for (int j = 0; j < 4; ++j) {
                acc[i][j] = __builtin_amdgcn_mfma_f32_16x16x32_f16(
                    ah[i], blf[j], acc[i][j], 0, 0, 0);
                acc[i][j] = __builtin_amdgcn_mfma_f32_16x16x32_f16(
                    al[i], bhf[j], acc[i][j], 0, 0, 0);
                acc[i][j] = __builtin_amdgcn_mfma_f32_16x16x32_f16(
                    ah[i], bhf[j], acc[i][j], 0, 0, 0);
            }
    }

    const int orow = (lane >> 4) << 2;
    #pragma unroll
    for (int i = 0; i < 4; ++i) {
        const int gr = (mt << 7) + (wm << 6) + (i << 4) + orow;
        #pragma unroll
        for (int j = 0; j < 4; ++j) {
            const int gc = nt * 128 + (wn << 6) + (j << 4) + (lane & 15);
            #pragma unroll
            for (int r = 0; r < 4; ++r)
                atomicAdd(&out[(size_t)(gr + r) * NSTR + gc], acc[i][j][r]);
        }
    }
}

// ---------------------------------------------------------------------------
extern "C" void kernel_launch(void* const* d_in, const int* in_sizes, int n_in,
                              void* d_out, int out_size, void* d_ws, size_t ws_size,
                              hipStream_t stream) {
    const float* x    = (const float*)d_in[0];
    const float* w    = (const float*)d_in[1];
    const float* Minv = (const float*)d_in[2];

    float* enc = (float*)d_out;          // encoded: 1024*1024
    float* dec = enc + MM;               // decoded: 1024*512

    // ws (floats): adb MM | t MM | xkp 2*MM | halves: bh,bl,Th,Tl,ench,encl MM,
    // wsh,wsl MM/2 | solved[1025] + barrier words. ~30 MB.
    float* ws  = (float*)d_ws;
    float* adb = ws;
    float* t   = ws + (size_t)MM;
    float* xkp = ws + 2 * (size_t)MM;

    _Float16* bh   = (_Float16*)(ws + 4 * (size_t)MM);
    _Float16* bl   = bh + (size_t)MM;
    _Float16* Th   = bl + (size_t)MM;
    _Float16* Tl   = Th + (size_t)MM;
    _Float16* ench = Tl + (size_t)MM;
    _Float16* encl = ench + (size_t)MM;
    _Float16* wsh  = encl + (size_t)MM;
    _Float16* wsl  = wsh + (size_t)(NIN * MOUT);
    int* solved    = (int*)(wsl + (size_t)(NIN * MOUT));
    int* bar       = solved + 1088;      // 16 groups x 32 ints (128 B) apart

    zero_init<<<(MM + 255) / 256, 256, 0, stream>>>(t, enc, dec, (float*)ench,
                                                    (float*)encl, solved);
    split_minv<<<512, 256, 0, stream>>>(Minv, Th, Tl);
    split_w<<<256, 256, 0, stream>>>(w, wsh, wsl);
    gemm_adb<<<256, 256, 0, stream>>>(x, w, adb, bh, bl);

    void* cargs[] = {(void*)&adb, (void*)&xkp, (void*)&t,
                     (void*)&bh,  (void*)&bl,  (void*)&Th, (void*)&Tl,
                     (void*)&enc, (void*)&ench, (void*)&encl, (void*)&solved,
                     (void*)&bar};
    // Cooperative launch used ONLY as a co-residency guarantee; the kernel
    // never calls grid.sync() — sync is 16 independent 32-block barriers.
    hipError_t e = hipLaunchCooperativeKernel(
        reinterpret_cast<void*>(admm_loop), dim3(512), dim3(256), cargs, 0, stream);
    if (e != hipSuccess) {
        // fallback: classic 2-kernel iteration loop
        for (int it = 0; it < MAX_ITERS; ++it) {
            gemm_xk<<<512, 256, 0, stream>>>(bh, bl, Th, Tl, xkp, solved);
            update<<<256, 256, 0, stream>>>(adb, xkp, t, bh, bl, enc, ench, encl,
                                            solved);
        }
    }

    mfma_dec<<<256, 256, 0, stream>>>(ench, encl, wsh, wsl, dec);
}

// Round 3
// 2900.443 us; speedup vs baseline: 8.5927x; 3.7303x over previous
//
#include <hip/hip_runtime.h>

typedef _Float16 half8 __attribute__((ext_vector_type(8)));
typedef _Float16 half4 __attribute__((ext_vector_type(4)));
typedef float floatx4 __attribute__((ext_vector_type(4)));

static constexpr int BATCH = 1024;
static constexpr int NIN   = 512;    // in_features
static constexpr int MOUT  = 1024;   // out_features
static constexpr float LAMBD = 0.2f;
static constexpr float TOLF  = 1e-4f;
static constexpr int MAX_ITERS = 100;
static constexpr int MM = BATCH * MOUT;   // 1M elements

// Fragment-swizzled layout for 16x16x32 MFMA operands (A: rows, B: cols), f16:
//   flat = ((tile16*32 + kchunk32)*64 + lane)*8 + elem
//   lane = (idx&15) | (((k>>3)&3)<<4), elem = k&7
__device__ __forceinline__ size_t swz(int idx, int k) {
    return ((((size_t)(idx >> 4) * 32 + (k >> 5)) * 64 +
             ((idx & 15) | (((k >> 3) & 3) << 4))) << 3) + (k & 7);
}

__device__ __forceinline__ float shrinkf(float t) {
    float a = fabsf(t) - LAMBD;
    return a > 0.f ? copysignf(a, t) : 0.f;
}

// ---------------------------------------------------------------------------
// XCD-local 32-block barrier. All 32 members of a stripe share one XCD
// (bid%8 pinning), so stores are visible at the XCD's L2 (write-through L1)
// once vmcnt drains at __syncthreads. Arrive/spin on relaxed atomics (bypass
// L1); then invalidate only L1 (buffer_inv sc0). NO buffer_wbl2 / L2 inv —
// that full-L2 maintenance was round-2's 3.2 GB/dispatch HBM round-trip.
// cnt counts arrivals monotonically (no reset race); gen is monotonic seq.
// ---------------------------------------------------------------------------
__device__ __forceinline__ void gbar32(int* cnt, int* gen, int seq) {
    __syncthreads();                       // drains vmcnt: stores at L2
    if (threadIdx.x == 0) {
        int old = atomicAdd(cnt, 1);       // device-scope RMW, L1-bypassing
        if (old == (seq << 5) - 1) {       // 32*seq-1: last arriver
            __hip_atomic_store(gen, seq, __ATOMIC_RELAXED,
                               __HIP_MEMORY_SCOPE_AGENT);
        } else {
            while (__hip_atomic_load(gen, __ATOMIC_RELAXED,
                                     __HIP_MEMORY_SCOPE_AGENT) < seq)
                __builtin_amdgcn_s_sleep(1);
        }
    }
    __syncthreads();
    asm volatile("buffer_inv sc0" ::: "memory");   // L1-only invalidate
}

// ---------------------------------------------------------------------------
// zero-init: t, enc, dec, swizzled enc halves, solved + barrier region
// ---------------------------------------------------------------------------
__global__ __launch_bounds__(256) void zero_init(float* t, float* enc,
                                                 float* dec, float* ench_f,
                                                 float* encl_f, int* solved) {
    int i = blockIdx.x * 256 + threadIdx.x;
    if (i < MM) { t[i] = 0.f; enc[i] = 0.f; }
    if (i < MM / 2) { dec[i] = 0.f; ench_f[i] = 0.f; encl_f[i] = 0.f; }
    if (i < 4096) solved[i] = 0;   // solved[0..1023] + barrier words @ +1088
}

// ---------------------------------------------------------------------------
// Th/Tl = B-fragment-swizzled split-f16 of Minv (col=n in 1024, k in 1024).
// ---------------------------------------------------------------------------
__global__ __launch_bounds__(256) void split_minv(const float* __restrict__ Minv,
                                                  _Float16* __restrict__ Th,
                                                  _Float16* __restrict__ Tl) {
    int g = blockIdx.x * 256 + threadIdx.x;   // 131072 threads
    int n = g & 1023, k0 = (g >> 10) << 3;
    half8 h, l;
    #pragma unroll
    for (int e = 0; e < 8; ++e) {
        float val = Minv[(size_t)(k0 + e) * MOUT + n];
        _Float16 hh = (_Float16)val;
        h[e] = hh;
        l[e] = (_Float16)(val - (float)hh);
    }
    size_t off = swz(n, k0);
    *(half8*)&Th[off] = h;
    *(half8*)&Tl[off] = l;
}

// ---------------------------------------------------------------------------
// wsh/wsl = B-fragment-swizzled split-f16 of weight (col=n in 512, k in 1024).
// ---------------------------------------------------------------------------
__global__ __launch_bounds__(256) void split_w(const float* __restrict__ w,
                                               _Float16* __restrict__ wsh,
                                               _Float16* __restrict__ wsl) {
    int g = blockIdx.x * 256 + threadIdx.x;   // 65536 threads
    int n = g & 511, k0 = (g >> 9) << 3;
    half8 h, l;
    #pragma unroll
    for (int e = 0; e < 8; ++e) {
        float val = w[(size_t)(k0 + e) * NIN + n];
        _Float16 hh = (_Float16)val;
        h[e] = hh;
        l[e] = (_Float16)(val - (float)hh);
    }
    size_t off = swz(n, k0);
    *(half8*)&wsh[off] = h;
    *(half8*)&wsl[off] = l;
}

// ---------------------------------------------------------------------------
// adb = x @ w^T (fp32, once). Epilogue emits beff = adb as A-swizzled h/l.
// ---------------------------------------------------------------------------
__global__ __launch_bounds__(256) void gemm_adb(const float* __restrict__ x,
                                                const float* __restrict__ w,
                                                float* __restrict__ adb,
                                                _Float16* __restrict__ bh,
                                                _Float16* __restrict__ bl) {
    __shared__ float As[16][68];
    __shared__ float Bs[16][68];
    const int tid = threadIdx.x;
    const int i0 = (blockIdx.x >> 4) * 64, j0 = (blockIdx.x & 15) * 64;
    const int tx = tid & 15, ty = tid >> 4;
    const int lr = tid >> 2, lk = (tid & 3) << 2;
    float acc[4][4] = {};
    for (int k0 = 0; k0 < NIN; k0 += 16) {
        float4 a4 = *(const float4*)&x[(i0 + lr) * NIN + k0 + lk];
        As[lk + 0][lr] = a4.x; As[lk + 1][lr] = a4.y;
        As[lk + 2][lr] = a4.z; As[lk + 3][lr] = a4.w;
        float4 b4 = *(const float4*)&w[(j0 + lr) * NIN + k0 + lk];
        Bs[lk + 0][lr] = b4.x; Bs[lk + 1][lr] = b4.y;
        Bs[lk + 2][lr] = b4.z; Bs[lk + 3][lr] = b4.w;
        __syncthreads();
        #pragma unroll
        for (int kk = 0; kk < 16; ++kk) {
            float4 a_ = *(const float4*)&As[kk][ty << 2];
            float4 b_ = *(const float4*)&Bs[kk][tx << 2];
            #pragma unroll
            for (int r = 0; r < 4; ++r) {
                float av = r == 0 ? a_.x : r == 1 ? a_.y : r == 2 ? a_.z : a_.w;
                acc[r][0] = fmaf(av, b_.x, acc[r][0]);
                acc[r][1] = fmaf(av, b_.y, acc[r][1]);
                acc[r][2] = fmaf(av, b_.z, acc[r][2]);
                acc[r][3] = fmaf(av, b_.w, acc[r][3]);
            }
        }
        __syncthreads();
    }
    const int k4 = j0 + (tx << 2);
    #pragma unroll
    for (int r = 0; r < 4; ++r) {
        const int row = i0 + (ty << 2) + r;
        *(float4*)&adb[(size_t)row * MOUT + k4] =
            make_float4(acc[r][0], acc[r][1], acc[r][2], acc[r][3]);
        half4 h, l;
        #pragma unroll
        for (int e = 0; e < 4; ++e) {
            _Float16 hh = (_Float16)acc[r][e];
            h[e] = hh;
            l[e] = (_Float16)(acc[r][e] - (float)hh);
        }
        size_t off = swz(row, k4);
        *(half4*)&bh[off] = h;
        *(half4*)&bl[off] = l;
    }
}

// ---------------------------------------------------------------------------
// FUSED persistent ADMM loop, XCD-PINNED stripes + L1-only barriers.
// Stripe mt's 32 blocks (16 nt x 2 c) all have bid%8 == mt%8, so (given the
// measured round-robin bid->XCD dispatch) they share one XCD's L2: all
// xkp/beff/solved handoffs are L2-coherent after a vmcnt drain, and the
// barrier needs no L2 writeback/invalidate. Iteration math is bitwise
// identical to the verified round-2 kernel.
// ---------------------------------------------------------------------------
__global__ __launch_bounds__(256, 2)
void admm_loop(const float* __restrict__ adb, float* __restrict__ xkp,
               float* __restrict__ tbuf,
               _Float16* __restrict__ bh, _Float16* __restrict__ bl,
               const _Float16* __restrict__ Th, const _Float16* __restrict__ Tl,
               float* __restrict__ enc, _Float16* __restrict__ ench,
               _Float16* __restrict__ encl, int* __restrict__ solved,
               int* __restrict__ bar) {
    const int bid = blockIdx.x;
    const int tid = threadIdx.x, lane = tid & 63;

    // XCD-pinned mapping: x = bid%8 is the (assumed) XCD; dispatch round
    // mseq = bid/8. Stripes 0..7 are round-1 blocks, 8..15 round-2.
    const int x = bid & 7, mseq = bid >> 3;
    const int mt = (mseq < 32) ? x : x + 8;
    const int j  = mseq & 31;              // member 0..31 within stripe
    const int c  = j & 1;                  // K-half
    const int nt = j >> 1;                 // N-tile
    const int m0 = mt << 6, n0 = nt << 6;
    const int wv = tid >> 6;
    const int wm = (wv >> 1) & 1, wn = wv & 1;
    const int kf0 = c << 4;                // first k32-chunk of this K-half
    // wave wv stages array wv: 0=Ah(bh) 1=Al(bl) 2=Bh(Th) 3=Bl(Tl)
    const _Float16* sarr = (wv == 0) ? bh : (wv == 1) ? bl : (wv == 2) ? Th : Tl;
    const int stile = (wv < 2) ? (mt << 2) : (nt << 2);

    __shared__ _Float16 Ash[16 * 512];     // 16 KB

    // per-stripe barrier words (128 B apart per stripe)
    int* gcnt = bar + (mt << 5);
    int* ggen = bar + (mt << 5) + 16;

    // update-phase: 2 rows per block (waves 0-1), covering stripe mt
    const int urow = m0 + (j << 1) + wv;

    for (int it = 0; it < MAX_ITERS; ++it) {
        // ================= GEMM phase =================
        floatx4 acc[2][2] = {};
        for (int s = 0; s < 16; ++s) {
            #pragma unroll
            for (int i = 0; i < 4; ++i) {
                const _Float16* src = sarr +
                    ((((size_t)(stile + i) * 32 + kf0 + s) << 9) +
                     ((size_t)lane << 3));
                __builtin_amdgcn_global_load_lds(
                    (const __attribute__((address_space(1))) void*)src,
                    (__attribute__((address_space(3))) void*)
                        &Ash[(((wv << 2) + i) << 9)],
                    16, 0, 0);
            }
            __syncthreads();

            half8 ah[2], al[2], bhf[2], blf[2];
            #pragma unroll
            for (int i = 0; i < 2; ++i) {
                const int at = (wm << 1) + i;
                ah[i]  = *(const half8*)&Ash[((0 << 11) + (at << 9)) + (lane << 3)];
                al[i]  = *(const half8*)&Ash[((1 << 11) + (at << 9)) + (lane << 3)];
                const int bt = (wn << 1) + i;
                bhf[i] = *(const half8*)&Ash[((2 << 11) + (bt << 9)) + (lane << 3)];
                blf[i] = *(const half8*)&Ash[((3 << 11) + (bt << 9)) + (lane << 3)];
            }
            #pragma unroll
            for (int i = 0; i < 2; ++i)
                #pragma unroll
                for (int jj = 0; jj < 2; ++jj) {
                    acc[i][jj] = __builtin_amdgcn_mfma_f32_16x16x32_f16(
                        ah[i], blf[jj], acc[i][jj], 0, 0, 0);
                    acc[i][jj] = __builtin_amdgcn_mfma_f32_16x16x32_f16(
                        al[i], bhf[jj], acc[i][jj], 0, 0, 0);
                    acc[i][jj] = __builtin_amdgcn_mfma_f32_16x16x32_f16(
                        ah[i], bhf[jj], acc[i][jj], 0, 0, 0);
                }
            __syncthreads();
        }
        // C/D: col = lane&15, row = (lane>>4)*4 + reg  [m89 verified]
        {
            float* op = xkp + (size_t)c * MM;
            const int orow = (lane >> 4) << 2;
            #pragma unroll
            for (int i = 0; i < 2; ++i) {
                const int gr = m0 + (wm << 5) + (i << 4) + orow;
                #pragma unroll
                for (int jj = 0; jj < 2; ++jj) {
                    const int gc = n0 + (wn << 5) + (jj << 4) + (lane & 15);
                    #pragma unroll
                    for (int r = 0; r < 4; ++r)
                        op[(size_t)(gr + r) * MOUT + gc] = acc[i][jj][r];
                }
            }
        }
        gbar32(gcnt, ggen, 2 * it + 1);

        // ================= update phase =================
        if (wv < 2 && !((volatile const int*)solved)[urow]) {
            const int row = urow;
            float vn[16];
            float dx2 = 0.f, x2 = 0.f;
            #pragma unroll
            for (int cch = 0; cch < 4; ++cch) {
                const int k4 = (cch << 8) + (lane << 2);
                const size_t jj = ((size_t)row << 10) + k4;
                float4 p0 = *(const float4*)&xkp[jj];
                float4 p1 = *(const float4*)&xkp[(size_t)MM + jj];
                float4 tp = *(const float4*)&tbuf[jj];
                float4 aa = *(const float4*)&adb[jj];
                float kxa[4] = {p0.x + p1.x, p0.y + p1.y, p0.z + p1.z, p0.w + p1.w};
                float tpa[4] = {tp.x, tp.y, tp.z, tp.w};
                float aaa[4] = {aa.x, aa.y, aa.z, aa.w};
                float tna[4];
                half4 h, l;
                #pragma unroll
                for (int e = 0; e < 4; ++e) {
                    float vprev = shrinkf(tpa[e]);
                    float uu = tpa[e] - vprev;
                    float tn = kxa[e] + uu;          // = u + xk  (ref order)
                    float vv = shrinkf(tn);
                    float un = tn - vv;              // u_new = (u + xk) - v_new
                    float d = vv - vprev;
                    dx2 += d * d;
                    x2 += vv * vv;
                    vn[(cch << 2) + e] = vv;
                    tna[e] = tn;
                    float nb = (aaa[e] + vv) - un;   // (adb + v_new) - u_new
                    _Float16 hh = (_Float16)nb;
                    h[e] = hh;
                    l[e] = (_Float16)(nb - (float)hh);
                }
                *(float4*)&tbuf[jj] = make_float4(tna[0], tna[1], tna[2], tna[3]);
                size_t off = swz(row, k4);
                *(half4*)&bh[off] = h;
                *(half4*)&bl[off] = l;
            }
            #pragma unroll
            for (int off = 32; off; off >>= 1) {
                dx2 += __shfl_xor(dx2, off);
                x2  += __shfl_xor(x2, off);
            }
            if (dx2 < TOLF * TOLF * x2) {   // x2==0 -> false (NaN semantics)
                #pragma unroll
                for (int cch = 0; cch < 4; ++cch) {
                    const int k4 = (cch << 8) + (lane << 2);
                    const size_t jj = ((size_t)row << 10) + k4;
                    float va[4] = {vn[(cch << 2) + 0], vn[(cch << 2) + 1],
                                   vn[(cch << 2) + 2], vn[(cch << 2) + 3]};
                    *(float4*)&enc[jj] = make_float4(va[0], va[1], va[2], va[3]);
                    half4 h, l;
                    #pragma unroll
                    for (int e = 0; e < 4; ++e) {
                        _Float16 hh = (_Float16)va[e];
                        h[e] = hh;
                        l[e] = (_Float16)(va[e] - (float)hh);
                    }
                    size_t off = swz(row, k4);
                    *(half4*)&ench[off] = h;
                    *(half4*)&encl[off] = l;
                }
                if (lane == 0) ((volatile int*)solved)[row] = 1;
            }
        }
        gbar32(gcnt, ggen, 2 * it + 2);

        // stripe-local exact early exit (stripe-uniform decision)
        if (__ballot(((volatile const int*)solved)[m0 + lane] != 0) == ~0ull)
            break;
    }
}

// ---------------------------------------------------------------------------
// Fallback (non-persistent) iteration kernels — proven baseline path.
// ---------------------------------------------------------------------------
__global__ __launch_bounds__(256, 2)
void gemm_xk(const _Float16* __restrict__ bh, const _Float16* __restrict__ bl,
             const _Float16* __restrict__ Th, const _Float16* __restrict__ Tl,
             float* __restrict__ xkp, const int* __restrict__ solved) {
    const int bid = blockIdx.x;
    const int c = bid & 1, t = bid >> 1;
    const int mt = t >> 4, nt = t & 15;
    const int m0 = mt << 6, n0 = nt << 6;
    const int tid = threadIdx.x, lane = tid & 63;

    bool done = ((volatile const int*)solved)[m0 + lane] != 0;
    if (__ballot(done) == ~0ull) return;

    __shared__ _Float16 Ash[16 * 512];

    const int wv = tid >> 6;
    const int wm = (wv >> 1) & 1, wn = wv & 1;
    const int kf0 = c << 4;

    const _Float16* sarr = (wv == 0) ? bh : (wv == 1) ? bl : (wv == 2) ? Th : Tl;
    const int stile = (wv < 2) ? (mt << 2) : (nt << 2);

    floatx4 acc[2][2] = {};
    for (int s = 0; s < 16; ++s) {
        #pragma unroll
        for (int i = 0; i < 4; ++i) {
            const _Float16* src = sarr +
                ((((size_t)(stile + i) * 32 + kf0 + s) << 9) + ((size_t)lane << 3));
            __builtin_amdgcn_global_load_lds(
                (const __attribute__((address_space(1))) void*)src,
                (__attribute__((address_space(3))) void*)
                    &Ash[(((wv << 2) + i) << 9)],
                16, 0, 0);
        }
        __syncthreads();

        half8 ah[2], al[2], bhf[2], blf[2];
        #pragma unroll
        for (int i = 0; i < 2; ++i) {
            const int at = (wm << 1) + i;
            ah[i]  = *(const half8*)&Ash[((0 << 11) + (at << 9)) + (lane << 3)];
            al[i]  = *(const half8*)&Ash[((1 << 11) + (at << 9)) + (lane << 3)];
            const int bt = (wn << 1) + i;
            bhf[i] = *(const half8*)&Ash[((2 << 11) + (bt << 9)) + (lane << 3)];
            blf[i] = *(const half8*)&Ash[((3 << 11) + (bt << 9)) + (lane << 3)];
        }
        #pragma unroll
        for (int i = 0; i < 2; ++i)
            #pragma unroll
            for (int jj = 0; jj < 2; ++jj) {
                acc[i][jj] = __builtin_amdgcn_mfma_f32_16x16x32_f16(
                    ah[i], blf[jj], acc[i][jj], 0, 0, 0);
                acc[i][jj] = __builtin_amdgcn_mfma_f32_16x16x32_f16(
                    al[i], bhf[jj], acc[i][jj], 0, 0, 0);
                acc[i][jj] = __builtin_amdgcn_mfma_f32_16x16x32_f16(
                    ah[i], bhf[jj], acc[i][jj], 0, 0, 0);
            }
        __syncthreads();
    }

    float* op = xkp + (size_t)c * MM;
    const int orow = (lane >> 4) << 2;
    #pragma unroll
    for (int i = 0; i < 2; ++i) {
        const int gr = m0 + (wm << 5) + (i << 4) + orow;
        #pragma unroll
        for (int jj = 0; jj < 2; ++jj) {
            const int gc = n0 + (wn << 5) + (jj << 4) + (lane & 15);
            #pragma unroll
            for (int r = 0; r < 4; ++r)
                op[(size_t)(gr + r) * MOUT + gc] = acc[i][jj][r];
        }
    }
}

__global__ __launch_bounds__(256) void update(const float* __restrict__ adb,
                                              const float* __restrict__ xkp,
                                              float* __restrict__ t,
                                              _Float16* __restrict__ bh,
                                              _Float16* __restrict__ bl,
                                              float* __restrict__ enc,
                                              _Float16* __restrict__ ench,
                                              _Float16* __restrict__ encl,
                                              int* solved) {
    const int tid = threadIdx.x, lane = tid & 63;
    const int row = (blockIdx.x << 2) + (tid >> 6);
    if (((volatile const int*)solved)[row]) return;

    float vn[16];
    float dx2 = 0.f, x2 = 0.f;
    #pragma unroll
    for (int cch = 0; cch < 4; ++cch) {
        const int k4 = (cch << 8) + (lane << 2);
        const size_t j = ((size_t)row << 10) + k4;
        float4 p0 = *(const float4*)&xkp[j];
        float4 p1 = *(const float4*)&xkp[(size_t)MM + j];
        float4 tp = *(const float4*)&t[j];
        float4 aa = *(const float4*)&adb[j];
        float kxa[4] = {p0.x + p1.x, p0.y + p1.y, p0.z + p1.z, p0.w + p1.w};
        float tpa[4] = {tp.x, tp.y, tp.z, tp.w};
        float aaa[4] = {aa.x, aa.y, aa.z, aa.w};
        float tna[4];
        half4 h, l;
        #pragma unroll
        for (int e = 0; e < 4; ++e) {
            float vprev = shrinkf(tpa[e]);
            float uu = tpa[e] - vprev;
            float tn = kxa[e] + uu;
            float vv = shrinkf(tn);
            float un = tn - vv;
            float d = vv - vprev;
            dx2 += d * d;
            x2 += vv * vv;
            vn[(cch << 2) + e] = vv;
            tna[e] = tn;
            float nb = (aaa[e] + vv) - un;
            _Float16 hh = (_Float16)nb;
            h[e] = hh;
            l[e] = (_Float16)(nb - (float)hh);
        }
        *(float4*)&t[j] = make_float4(tna[0], tna[1], tna[2], tna[3]);
        size_t off = swz(row, k4);
        *(half4*)&bh[off] = h;
        *(half4*)&bl[off] = l;
    }
    #pragma unroll
    for (int off = 32; off; off >>= 1) {
        dx2 += __shfl_xor(dx2, off);
        x2  += __shfl_xor(x2, off);
    }
    if (dx2 < TOLF * TOLF * x2) {
        #pragma unroll
        for (int cch = 0; cch < 4; ++cch) {
            const int k4 = (cch << 8) + (lane << 2);
            const size_t j = ((size_t)row << 10) + k4;
            float va[4] = {vn[(cch << 2) + 0], vn[(cch << 2) + 1],
                           vn[(cch << 2) + 2], vn[(cch << 2) + 3]};
            *(float4*)&enc[j] = make_float4(va[0], va[1], va[2], va[3]);
            half4 h, l;
            #pragma unroll
            for (int e = 0; e < 4; ++e) {
                _Float16 hh = (_Float16)va[e];
                h[e] = hh;
                l[e] = (_Float16)(va[e] - (float)hh);
            }
            size_t off = swz(row, k4);
            *(half4*)&ench[off] = h;
            *(half4*)&encl[off] = l;
        }
        if (lane == 0) ((volatile int*)solved)[row] = 1;
    }
}

// ---------------------------------------------------------------------------
// dec = enc @ w, split-f16 MFMA, runs ONCE. 128x128 tile, S=8 whole-partition
// A staging (64 KB), one barrier, atomicAdd epilogue (one-time cost).
// ---------------------------------------------------------------------------
__global__ __launch_bounds__(256, 2)
void mfma_dec(const _Float16* __restrict__ Ahg, const _Float16* __restrict__ Alg,
              const _Float16* __restrict__ Bhg, const _Float16* __restrict__ Blg,
              float* __restrict__ out) {
    constexpr int NSTR = NIN;              // 512
    constexpr int NT = NSTR / 128;         // 4
    const int bid = blockIdx.x;
    const int c = bid & 7, t = bid >> 3;
    const int mt = t / NT, nt = t % NT;
    const int tid = threadIdx.x, lane = tid & 63;

    __shared__ _Float16 Ash[64 * 512];     // 64 KB

    const int wv = tid >> 6;
    const int wm = (tid >> 7) & 1, wn = (tid >> 6) & 1;
    const int kf0 = c << 2;

    #pragma unroll
    for (int i = 0; i < 16; ++i) {
        const int chunk = (wv << 4) + i;
        const int rt = chunk >> 3, kc = (chunk >> 1) & 3, hl = chunk & 1;
        const _Float16* src = (hl ? Alg : Ahg) +
            ((((size_t)((mt << 3) + rt) * 32 + kf0 + kc) << 9) + ((size_t)lane << 3));
        __builtin_amdgcn_global_load_lds(
            (const __attribute__((address_space(1))) void*)src,
            (__attribute__((address_space(3))) void*)&Ash[(size_t)chunk << 9],
            16, 0, 0);
    }
    __syncthreads();

    const int ct0 = nt * 8 + (wn << 2);
    const _Float16* pBh = Bhg + ((((size_t)ct0 * 32 + kf0) * 64 + lane) << 3);
    const _Float16* pBl = Blg + ((((size_t)ct0 * 32 + kf0) * 64 + lane) << 3);

    floatx4 acc[4][4] = {};
    #pragma unroll
    for (int s = 0; s < 4; ++s) {
        half8 bhf[4], blf[4];
        #pragma unroll
        for (int j = 0; j < 4; ++j) {
            bhf[j] = *(const half8*)(pBh + ((size_t)j << 14) + ((size_t)s << 9));
            blf[j] = *(const half8*)(pBl + ((size_t)j << 14) + ((size_t)s << 9));
        }
        half8 ah[4], al[4];
        #pragma unroll
        for (int i = 0; i < 4; ++i) {
            const int rt = (wm << 2) + i;
            ah[i] = *(const half8*)&Ash[((((rt << 2) + s) << 1) << 9) + (lane << 3)];
            al[i] = *(const half8*)&Ash[(((((rt << 2) + s) << 1) + 1) << 9) + (lane << 3)];
        }
        #pragma unroll
        for (int i = 0; i < 4; ++i)
            #pragma unroll
            for (int j = 0; j < 4; ++j) {
                acc[i][j] = __builtin_amdgcn_mfma_f32_16x16x32_f16(
                    ah[i], blf[j], acc[i][j], 0, 0, 0);
                acc[i][j] = __builtin_amdgcn_mfma_f32_16x16x32_f16(
                    al[i], bhf[j], acc[i][j], 0, 0, 0);
                acc[i][j] = __builtin_amdgcn_mfma_f32_16x16x32_f16(
                    ah[i], bhf[j], acc[i][j], 0, 0, 0);
            }
    }

    const int orow = (lane >> 4) << 2;
    #pragma unroll
    for (int i = 0; i < 4; ++i) {
        const int gr = (mt << 7) + (wm << 6) + (i << 4) + orow;
        #pragma unroll
        for (int j = 0; j < 4; ++j) {
            const int gc = nt * 128 + (wn << 6) + (j << 4) + (lane & 15);
            #pragma unroll
            for (int r = 0; r < 4; ++r)
                atomicAdd(&out[(size_t)(gr + r) * NSTR + gc], acc[i][j][r]);
        }
    }
}

// ---------------------------------------------------------------------------
extern "C" void kernel_launch(void* const* d_in, const int* in_sizes, int n_in,
                              void* d_out, int out_size, void* d_ws, size_t ws_size,
                              hipStream_t stream) {
    const float* x    = (const float*)d_in[0];
    const float* w    = (const float*)d_in[1];
    const float* Minv = (const float*)d_in[2];

    float* enc = (float*)d_out;          // encoded: 1024*1024
    float* dec = enc + MM;               // decoded: 1024*512

    // ws (floats): adb MM | t MM | xkp 2*MM | halves: bh,bl,Th,Tl,ench,encl MM,
    // wsh,wsl MM/2 | solved[1024] + barrier words. ~30 MB.
    float* ws  = (float*)d_ws;
    float* adb = ws;
    float* t   = ws + (size_t)MM;
    float* xkp = ws + 2 * (size_t)MM;

    _Float16* bh   = (_Float16*)(ws + 4 * (size_t)MM);
    _Float16* bl   = bh + (size_t)MM;
    _Float16* Th   = bl + (size_t)MM;
    _Float16* Tl   = Th + (size_t)MM;
    _Float16* ench = Tl + (size_t)MM;
    _Float16* encl = ench + (size_t)MM;
    _Float16* wsh  = encl + (size_t)MM;
    _Float16* wsl  = wsh + (size_t)(NIN * MOUT);
    int* solved    = (int*)(wsl + (size_t)(NIN * MOUT));
    int* bar       = solved + 1088;      // 16 stripes x 32 ints (128 B) apart

    zero_init<<<(MM + 255) / 256, 256, 0, stream>>>(t, enc, dec, (float*)ench,
                                                    (float*)encl, solved);
    split_minv<<<512, 256, 0, stream>>>(Minv, Th, Tl);
    split_w<<<256, 256, 0, stream>>>(w, wsh, wsl);
    gemm_adb<<<256, 256, 0, stream>>>(x, w, adb, bh, bl);

    void* cargs[] = {(void*)&adb, (void*)&xkp, (void*)&t,
                     (void*)&bh,  (void*)&bl,  (void*)&Th, (void*)&Tl,
                     (void*)&enc, (void*)&ench, (void*)&encl, (void*)&solved,
                     (void*)&bar};
    // Cooperative launch used ONLY as a co-residency guarantee (deadlock
    // safety for the spin barriers); no grid.sync() is ever called.
    hipError_t e = hipLaunchCooperativeKernel(
        reinterpret_cast<void*>(admm_loop), dim3(512), dim3(256), cargs, 0, stream);
    if (e != hipSuccess) {
        // fallback: classic 2-kernel iteration loop
        for (int it = 0; it < MAX_ITERS; ++it) {
            gemm_xk<<<512, 256, 0, stream>>>(bh, bl, Th, Tl, xkp, solved);
            update<<<256, 256, 0, stream>>>(adb, xkp, t, bh, bl, enc, ench, encl,
                                            solved);
        }
    }

    mfma_dec<<<256, 256, 0, stream>>>(ench, encl, wsh, wsl, dec);
}

// Round 4
// 2086.195 us; speedup vs baseline: 11.9465x; 1.3903x over previous
//
#include <hip/hip_runtime.h>

typedef _Float16 half8 __attribute__((ext_vector_type(8)));
typedef _Float16 half4 __attribute__((ext_vector_type(4)));
typedef float floatx4 __attribute__((ext_vector_type(4)));

static constexpr int BATCH = 1024;
static constexpr int NIN   = 512;    // in_features
static constexpr int MOUT  = 1024;   // out_features
static constexpr float LAMBD = 0.2f;
static constexpr float TOLF  = 1e-4f;
static constexpr int MAX_ITERS = 100;
static constexpr int MM = BATCH * MOUT;   // 1M elements

// Fragment-swizzled layout for 16x16x32 MFMA operands (A: rows, B: cols), f16:
//   flat = ((tile16*32 + kchunk32)*64 + lane)*8 + elem
//   lane = (idx&15) | (((k>>3)&3)<<4), elem = k&7
__device__ __forceinline__ size_t swz(int idx, int k) {
    return ((((size_t)(idx >> 4) * 32 + (k >> 5)) * 64 +
             ((idx & 15) | (((k >> 3) & 3) << 4))) << 3) + (k & 7);
}

__device__ __forceinline__ float shrinkf(float t) {
    float a = fabsf(t) - LAMBD;
    return a > 0.f ? copysignf(a, t) : 0.f;
}

// ---------------------------------------------------------------------------
// XCD-local 64-block barrier (one stripe = one XCD under bid%8 round-robin,
// validated by round-3 pass). Stores are L2-visible after the vmcnt drain in
// __syncthreads (write-through L1); arrive/spin on L1-bypassing atomics; then
// L1-only invalidate. No L2 writeback/invalidate.
// ---------------------------------------------------------------------------
__device__ __forceinline__ void gbar64(int* cnt, int* gen, int seq) {
    __syncthreads();                       // drains vmcnt: stores at L2
    if (threadIdx.x == 0) {
        int old = atomicAdd(cnt, 1);       // device-scope RMW, L1-bypassing
        if (old == (seq << 6) - 1) {       // 64*seq-1: last arriver
            __hip_atomic_store(gen, seq, __ATOMIC_RELAXED,
                               __HIP_MEMORY_SCOPE_AGENT);
        } else {
            while (__hip_atomic_load(gen, __ATOMIC_RELAXED,
                                     __HIP_MEMORY_SCOPE_AGENT) < seq)
                __builtin_amdgcn_s_sleep(1);
        }
    }
    __syncthreads();
    asm volatile("buffer_inv sc0" ::: "memory");   // L1-only invalidate
}

// ---------------------------------------------------------------------------
// zero-init: t, enc, dec, swizzled enc halves, solved + barrier region
// ---------------------------------------------------------------------------
__global__ __launch_bounds__(256) void zero_init(float* t, float* enc,
                                                 float* dec, float* ench_f,
                                                 float* encl_f, int* solved) {
    int i = blockIdx.x * 256 + threadIdx.x;
    if (i < MM) { t[i] = 0.f; enc[i] = 0.f; }
    if (i < MM / 2) { dec[i] = 0.f; ench_f[i] = 0.f; encl_f[i] = 0.f; }
    if (i < 4096) solved[i] = 0;   // solved[0..1023] + barrier words @ +1088
}

// ---------------------------------------------------------------------------
// Th/Tl = B-fragment-swizzled split-f16 of Minv (col=n in 1024, k in 1024).
// ---------------------------------------------------------------------------
__global__ __launch_bounds__(256) void split_minv(const float* __restrict__ Minv,
                                                  _Float16* __restrict__ Th,
                                                  _Float16* __restrict__ Tl) {
    int g = blockIdx.x * 256 + threadIdx.x;   // 131072 threads
    int n = g & 1023, k0 = (g >> 10) << 3;
    half8 h, l;
    #pragma unroll
    for (int e = 0; e < 8; ++e) {
        float val = Minv[(size_t)(k0 + e) * MOUT + n];
        _Float16 hh = (_Float16)val;
        h[e] = hh;
        l[e] = (_Float16)(val - (float)hh);
    }
    size_t off = swz(n, k0);
    *(half8*)&Th[off] = h;
    *(half8*)&Tl[off] = l;
}

// ---------------------------------------------------------------------------
// wsh/wsl = B-fragment-swizzled split-f16 of weight (col=n in 512, k in 1024).
// ---------------------------------------------------------------------------
__global__ __launch_bounds__(256) void split_w(const float* __restrict__ w,
                                               _Float16* __restrict__ wsh,
                                               _Float16* __restrict__ wsl) {
    int g = blockIdx.x * 256 + threadIdx.x;   // 65536 threads
    int n = g & 511, k0 = (g >> 9) << 3;
    half8 h, l;
    #pragma unroll
    for (int e = 0; e < 8; ++e) {
        float val = w[(size_t)(k0 + e) * NIN + n];
        _Float16 hh = (_Float16)val;
        h[e] = hh;
        l[e] = (_Float16)(val - (float)hh);
    }
    size_t off = swz(n, k0);
    *(half8*)&wsh[off] = h;
    *(half8*)&wsl[off] = l;
}

// ---------------------------------------------------------------------------
// adb = x @ w^T (fp32, once). Epilogue emits beff = adb as A-swizzled h/l.
// ---------------------------------------------------------------------------
__global__ __launch_bounds__(256) void gemm_adb(const float* __restrict__ x,
                                                const float* __restrict__ w,
                                                float* __restrict__ adb,
                                                _Float16* __restrict__ bh,
                                                _Float16* __restrict__ bl) {
    __shared__ float As[16][68];
    __shared__ float Bs[16][68];
    const int tid = threadIdx.x;
    const int i0 = (blockIdx.x >> 4) * 64, j0 = (blockIdx.x & 15) * 64;
    const int tx = tid & 15, ty = tid >> 4;
    const int lr = tid >> 2, lk = (tid & 3) << 2;
    float acc[4][4] = {};
    for (int k0 = 0; k0 < NIN; k0 += 16) {
        float4 a4 = *(const float4*)&x[(i0 + lr) * NIN + k0 + lk];
        As[lk + 0][lr] = a4.x; As[lk + 1][lr] = a4.y;
        As[lk + 2][lr] = a4.z; As[lk + 3][lr] = a4.w;
        float4 b4 = *(const float4*)&w[(j0 + lr) * NIN + k0 + lk];
        Bs[lk + 0][lr] = b4.x; Bs[lk + 1][lr] = b4.y;
        Bs[lk + 2][lr] = b4.z; Bs[lk + 3][lr] = b4.w;
        __syncthreads();
        #pragma unroll
        for (int kk = 0; kk < 16; ++kk) {
            float4 a_ = *(const float4*)&As[kk][ty << 2];
            float4 b_ = *(const float4*)&Bs[kk][tx << 2];
            #pragma unroll
            for (int r = 0; r < 4; ++r) {
                float av = r == 0 ? a_.x : r == 1 ? a_.y : r == 2 ? a_.z : a_.w;
                acc[r][0] = fmaf(av, b_.x, acc[r][0]);
                acc[r][1] = fmaf(av, b_.y, acc[r][1]);
                acc[r][2] = fmaf(av, b_.z, acc[r][2]);
                acc[r][3] = fmaf(av, b_.w, acc[r][3]);
            }
        }
        __syncthreads();
    }
    const int k4 = j0 + (tx << 2);
    #pragma unroll
    for (int r = 0; r < 4; ++r) {
        const int row = i0 + (ty << 2) + r;
        *(float4*)&adb[(size_t)row * MOUT + k4] =
            make_float4(acc[r][0], acc[r][1], acc[r][2], acc[r][3]);
        half4 h, l;
        #pragma unroll
        for (int e = 0; e < 4; ++e) {
            _Float16 hh = (_Float16)acc[r][e];
            h[e] = hh;
            l[e] = (_Float16)(acc[r][e] - (float)hh);
        }
        size_t off = swz(row, k4);
        *(half4*)&bh[off] = h;
        *(half4*)&bl[off] = l;
    }
}

// ---------------------------------------------------------------------------
// FUSED persistent ADMM loop, B-IN-LDS edition.
// 512 blocks (2/CU): 8 stripes (mt, 128 rows) x 32 nt (32 cols) x 2 c (512 k).
// Stripe = 64 blocks = all of XCD (bid%8 == mt). Each block's B slice
// (32 cols x 512 k, split h/l) = 64 KB, loaded into LDS ONCE and reused for
// all iterations -> zero per-iteration B traffic (round 3's 32 MB/iter L3
// refetch). A (bh/bl) is read global->VGPR each step: XCD-local L2 hits.
// Gemm inner loop is barrier-free. Update phase bitwise-identical math.
// ---------------------------------------------------------------------------
__global__ __launch_bounds__(256, 2)
void admm_loop(const float* __restrict__ adb, float* __restrict__ xkp,
               float* __restrict__ tbuf,
               _Float16* __restrict__ bh, _Float16* __restrict__ bl,
               const _Float16* __restrict__ Th, const _Float16* __restrict__ Tl,
               float* __restrict__ enc, _Float16* __restrict__ ench,
               _Float16* __restrict__ encl, int* __restrict__ solved,
               int* __restrict__ bar) {
    const int bid = blockIdx.x;
    const int tid = threadIdx.x, lane = tid & 63;
    const int wv = tid >> 6;

    // XCD-pinned mapping: stripe mt = bid%8; member = bid/8 in 0..63.
    const int mt = bid & 7;
    const int memb = bid >> 3;             // 0..63
    const int nt = memb >> 1;              // 0..31 (32-col tile)
    const int c  = memb & 1;               // K-half
    const int m0 = mt << 7;                // stripe base row (128 rows)
    const int n0 = nt << 5;                // tile base col (32 cols)

    __shared__ _Float16 Bs[64 * 512];      // 64 KB persistent B slice

    // ---- one-time B load: chunk = ((hl*2 + j)*16 + s), 16 chunks per wave
    #pragma unroll
    for (int i = 0; i < 16; ++i) {
        const int chunk = (wv << 4) + i;
        const int hl = chunk >> 5, ct = (chunk >> 4) & 1, s = chunk & 15;
        const _Float16* src = (hl ? Tl : Th) +
            ((((size_t)((nt << 1) + ct) * 32 + (c << 4) + s) << 9) +
             ((size_t)lane << 3));
        __builtin_amdgcn_global_load_lds(
            (const __attribute__((address_space(1))) void*)src,
            (__attribute__((address_space(3))) void*)&Bs[(size_t)chunk << 9],
            16, 0, 0);
    }
    __syncthreads();

    // per-stripe barrier words (128 B apart per stripe)
    int* gcnt = bar + (mt << 5);
    int* ggen = bar + (mt << 5) + 16;

    // update-phase: 2 rows per block (waves 0-1), covering stripe mt
    const int urow = m0 + (memb << 1) + wv;

    // wave's global row-tile base: each wave owns 32 rows (2 tiles)
    const int rt0 = (mt << 3) + (wv << 1);

    for (int it = 0; it < MAX_ITERS; ++it) {
        // ================= GEMM phase (no barriers inside) =================
        floatx4 acc[2][2] = {};
        #pragma unroll 2
        for (int s = 0; s < 16; ++s) {
            half8 bhf[2], blf[2], ah[2], al[2];
            #pragma unroll
            for (int j = 0; j < 2; ++j) {
                bhf[j] = *(const half8*)&Bs[(((j << 4) | s) << 9) + (lane << 3)];
                blf[j] = *(const half8*)&Bs[((((2 + j) << 4) | s) << 9) + (lane << 3)];
            }
            const size_t koff = ((size_t)((c << 4) + s)) << 9;
            #pragma unroll
            for (int i = 0; i < 2; ++i) {
                const size_t aoff =
                    (((size_t)(rt0 + i)) << 14) + koff + ((size_t)lane << 3);
                ah[i] = *(const half8*)&bh[aoff];
                al[i] = *(const half8*)&bl[aoff];
            }
            #pragma unroll
            for (int i = 0; i < 2; ++i)
                #pragma unroll
                for (int j = 0; j < 2; ++j) {
                    acc[i][j] = __builtin_amdgcn_mfma_f32_16x16x32_f16(
                        ah[i], blf[j], acc[i][j], 0, 0, 0);
                    acc[i][j] = __builtin_amdgcn_mfma_f32_16x16x32_f16(
                        al[i], bhf[j], acc[i][j], 0, 0, 0);
                    acc[i][j] = __builtin_amdgcn_mfma_f32_16x16x32_f16(
                        ah[i], bhf[j], acc[i][j], 0, 0, 0);
                }
        }
        // C/D: col = lane&15, row = (lane>>4)*4 + reg  [m89 verified]
        {
            float* op = xkp + (size_t)c * MM;
            const int orow = (lane >> 4) << 2;
            #pragma unroll
            for (int i = 0; i < 2; ++i) {
                const int gr = m0 + (wv << 5) + (i << 4) + orow;
                #pragma unroll
                for (int j = 0; j < 2; ++j) {
                    const int gc = n0 + (j << 4) + (lane & 15);
                    #pragma unroll
                    for (int r = 0; r < 4; ++r)
                        op[(size_t)(gr + r) * MOUT + gc] = acc[i][j][r];
                }
            }
        }
        gbar64(gcnt, ggen, 2 * it + 1);

        // ================= update phase =================
        if (wv < 2 && !((volatile const int*)solved)[urow]) {
            const int row = urow;
            float vn[16];
            float dx2 = 0.f, x2 = 0.f;
            #pragma unroll
            for (int cch = 0; cch < 4; ++cch) {
                const int k4 = (cch << 8) + (lane << 2);
                const size_t jj = ((size_t)row << 10) + k4;
                float4 p0 = *(const float4*)&xkp[jj];
                float4 p1 = *(const float4*)&xkp[(size_t)MM + jj];
                float4 tp = *(const float4*)&tbuf[jj];
                float4 aa = *(const float4*)&adb[jj];
                float kxa[4] = {p0.x + p1.x, p0.y + p1.y, p0.z + p1.z, p0.w + p1.w};
                float tpa[4] = {tp.x, tp.y, tp.z, tp.w};
                float aaa[4] = {aa.x, aa.y, aa.z, aa.w};
                float tna[4];
                half4 h, l;
                #pragma unroll
                for (int e = 0; e < 4; ++e) {
                    float vprev = shrinkf(tpa[e]);
                    float uu = tpa[e] - vprev;
                    float tn = kxa[e] + uu;          // = u + xk  (ref order)
                    float vv = shrinkf(tn);
                    float un = tn - vv;              // u_new = (u + xk) - v_new
                    float d = vv - vprev;
                    dx2 += d * d;
                    x2 += vv * vv;
                    vn[(cch << 2) + e] = vv;
                    tna[e] = tn;
                    float nb = (aaa[e] + vv) - un;   // (adb + v_new) - u_new
                    _Float16 hh = (_Float16)nb;
                    h[e] = hh;
                    l[e] = (_Float16)(nb - (float)hh);
                }
                *(float4*)&tbuf[jj] = make_float4(tna[0], tna[1], tna[2], tna[3]);
                size_t off = swz(row, k4);
                *(half4*)&bh[off] = h;
                *(half4*)&bl[off] = l;
            }
            #pragma unroll
            for (int off = 32; off; off >>= 1) {
                dx2 += __shfl_xor(dx2, off);
                x2  += __shfl_xor(x2, off);
            }
            if (dx2 < TOLF * TOLF * x2) {   // x2==0 -> false (NaN semantics)
                #pragma unroll
                for (int cch = 0; cch < 4; ++cch) {
                    const int k4 = (cch << 8) + (lane << 2);
                    const size_t jj = ((size_t)row << 10) + k4;
                    float va[4] = {vn[(cch << 2) + 0], vn[(cch << 2) + 1],
                                   vn[(cch << 2) + 2], vn[(cch << 2) + 3]};
                    *(float4*)&enc[jj] = make_float4(va[0], va[1], va[2], va[3]);
                    half4 h, l;
                    #pragma unroll
                    for (int e = 0; e < 4; ++e) {
                        _Float16 hh = (_Float16)va[e];
                        h[e] = hh;
                        l[e] = (_Float16)(va[e] - (float)hh);
                    }
                    size_t off = swz(row, k4);
                    *(half4*)&ench[off] = h;
                    *(half4*)&encl[off] = l;
                }
                if (lane == 0) ((volatile int*)solved)[row] = 1;
            }
        }
        gbar64(gcnt, ggen, 2 * it + 2);

        // stripe-local exact early exit over 128 rows (stripe-uniform)
        bool d0 = ((volatile const int*)solved)[m0 + lane] != 0;
        bool d1 = ((volatile const int*)solved)[m0 + 64 + lane] != 0;
        if ((__ballot(d0) & __ballot(d1)) == ~0ull) break;
    }
}

// ---------------------------------------------------------------------------
// Fallback (non-persistent) iteration kernels — proven baseline path.
// ---------------------------------------------------------------------------
__global__ __launch_bounds__(256, 2)
void gemm_xk(const _Float16* __restrict__ bh, const _Float16* __restrict__ bl,
             const _Float16* __restrict__ Th, const _Float16* __restrict__ Tl,
             float* __restrict__ xkp, const int* __restrict__ solved) {
    const int bid = blockIdx.x;
    const int c = bid & 1, t = bid >> 1;
    const int mt = t >> 4, nt = t & 15;
    const int m0 = mt << 6, n0 = nt << 6;
    const int tid = threadIdx.x, lane = tid & 63;

    bool done = ((volatile const int*)solved)[m0 + lane] != 0;
    if (__ballot(done) == ~0ull) return;

    __shared__ _Float16 Ash[16 * 512];

    const int wv = tid >> 6;
    const int wm = (wv >> 1) & 1, wn = wv & 1;
    const int kf0 = c << 4;

    const _Float16* sarr = (wv == 0) ? bh : (wv == 1) ? bl : (wv == 2) ? Th : Tl;
    const int stile = (wv < 2) ? (mt << 2) : (nt << 2);

    floatx4 acc[2][2] = {};
    for (int s = 0; s < 16; ++s) {
        #pragma unroll
        for (int i = 0; i < 4; ++i) {
            const _Float16* src = sarr +
                ((((size_t)(stile + i) * 32 + kf0 + s) << 9) + ((size_t)lane << 3));
            __builtin_amdgcn_global_load_lds(
                (const __attribute__((address_space(1))) void*)src,
                (__attribute__((address_space(3))) void*)
                    &Ash[(((wv << 2) + i) << 9)],
                16, 0, 0);
        }
        __syncthreads();

        half8 ah[2], al[2], bhf[2], blf[2];
        #pragma unroll
        for (int i = 0; i < 2; ++i) {
            const int at = (wm << 1) + i;
            ah[i]  = *(const half8*)&Ash[((0 << 11) + (at << 9)) + (lane << 3)];
            al[i]  = *(const half8*)&Ash[((1 << 11) + (at << 9)) + (lane << 3)];
            const int bt = (wn << 1) + i;
            bhf[i] = *(const half8*)&Ash[((2 << 11) + (bt << 9)) + (lane << 3)];
            blf[i] = *(const half8*)&Ash[((3 << 11) + (bt << 9)) + (lane << 3)];
        }
        #pragma unroll
        for (int i = 0; i < 2; ++i)
            #pragma unroll
            for (int jj = 0; jj < 2; ++jj) {
                acc[i][jj] = __builtin_amdgcn_mfma_f32_16x16x32_f16(
                    ah[i], blf[jj], acc[i][jj], 0, 0, 0);
                acc[i][jj] = __builtin_amdgcn_mfma_f32_16x16x32_f16(
                    al[i], bhf[jj], acc[i][jj], 0, 0, 0);
                acc[i][jj] = __builtin_amdgcn_mfma_f32_16x16x32_f16(
                    ah[i], bhf[jj], acc[i][jj], 0, 0, 0);
            }
        __syncthreads();
    }

    float* op = xkp + (size_t)c * MM;
    const int orow = (lane >> 4) << 2;
    #pragma unroll
    for (int i = 0; i < 2; ++i) {
        const int gr = m0 + (wm << 5) + (i << 4) + orow;
        #pragma unroll
        for (int jj = 0; jj < 2; ++jj) {
            const int gc = n0 + (wn << 5) + (jj << 4) + (lane & 15);
            #pragma unroll
            for (int r = 0; r < 4; ++r)
                op[(size_t)(gr + r) * MOUT + gc] = acc[i][jj][r];
        }
    }
}

__global__ __launch_bounds__(256) void update(const float* __restrict__ adb,
                                              const float* __restrict__ xkp,
                                              float* __restrict__ t,
                                              _Float16* __restrict__ bh,
                                              _Float16* __restrict__ bl,
                                              float* __restrict__ enc,
                                              _Float16* __restrict__ ench,
                                              _Float16* __restrict__ encl,
                                              int* solved) {
    const int tid = threadIdx.x, lane = tid & 63;
    const int row = (blockIdx.x << 2) + (tid >> 6);
    if (((volatile const int*)solved)[row]) return;

    float vn[16];
    float dx2 = 0.f, x2 = 0.f;
    #pragma unroll
    for (int cch = 0; cch < 4; ++cch) {
        const int k4 = (cch << 8) + (lane << 2);
        const size_t j = ((size_t)row << 10) + k4;
        float4 p0 = *(const float4*)&xkp[j];
        float4 p1 = *(const float4*)&xkp[(size_t)MM + j];
        float4 tp = *(const float4*)&t[j];
        float4 aa = *(const float4*)&adb[j];
        float kxa[4] = {p0.x + p1.x, p0.y + p1.y, p0.z + p1.z, p0.w + p1.w};
        float tpa[4] = {tp.x, tp.y, tp.z, tp.w};
        float aaa[4] = {aa.x, aa.y, aa.z, aa.w};
        float tna[4];
        half4 h, l;
        #pragma unroll
        for (int e = 0; e < 4; ++e) {
            float vprev = shrinkf(tpa[e]);
            float uu = tpa[e] - vprev;
            float tn = kxa[e] + uu;
            float vv = shrinkf(tn);
            float un = tn - vv;
            float d = vv - vprev;
            dx2 += d * d;
            x2 += vv * vv;
            vn[(cch << 2) + e] = vv;
            tna[e] = tn;
            float nb = (aaa[e] + vv) - un;
            _Float16 hh = (_Float16)nb;
            h[e] = hh;
            l[e] = (_Float16)(nb - (float)hh);
        }
        *(float4*)&t[j] = make_float4(tna[0], tna[1], tna[2], tna[3]);
        size_t off = swz(row, k4);
        *(half4*)&bh[off] = h;
        *(half4*)&bl[off] = l;
    }
    #pragma unroll
    for (int off = 32; off; off >>= 1) {
        dx2 += __shfl_xor(dx2, off);
        x2  += __shfl_xor(x2, off);
    }
    if (dx2 < TOLF * TOLF * x2) {
        #pragma unroll
        for (int cch = 0; cch < 4; ++cch) {
            const int k4 = (cch << 8) + (lane << 2);
            const size_t j = ((size_t)row << 10) + k4;
            float va[4] = {vn[(cch << 2) + 0], vn[(cch << 2) + 1],
                           vn[(cch << 2) + 2], vn[(cch << 2) + 3]};
            *(float4*)&enc[j] = make_float4(va[0], va[1], va[2], va[3]);
            half4 h, l;
            #pragma unroll
            for (int e = 0; e < 4; ++e) {
                _Float16 hh = (_Float16)va[e];
                h[e] = hh;
                l[e] = (_Float16)(va[e] - (float)hh);
            }
            size_t off = swz(row, k4);
            *(half4*)&ench[off] = h;
            *(half4*)&encl[off] = l;
        }
        if (lane == 0) ((volatile int*)solved)[row] = 1;
    }
}

// ---------------------------------------------------------------------------
// dec = enc @ w, split-f16 MFMA, runs ONCE. 128x128 tile, S=8 whole-partition
// A staging (64 KB), one barrier, atomicAdd epilogue (one-time cost).
// ---------------------------------------------------------------------------
__global__ __launch_bounds__(256, 2)
void mfma_dec(const _Float16* __restrict__ Ahg, const _Float16* __restrict__ Alg,
              const _Float16* __restrict__ Bhg, const _Float16* __restrict__ Blg,
              float* __restrict__ out) {
    constexpr int NSTR = NIN;              // 512
    constexpr int NT = NSTR / 128;         // 4
    const int bid = blockIdx.x;
    const int c = bid & 7, t = bid >> 3;
    const int mt = t / NT, nt = t % NT;
    const int tid = threadIdx.x, lane = tid & 63;

    __shared__ _Float16 Ash[64 * 512];     // 64 KB

    const int wv = tid >> 6;
    const int wm = (tid >> 7) & 1, wn = (tid >> 6) & 1;
    const int kf0 = c << 2;

    #pragma unroll
    for (int i = 0; i < 16; ++i) {
        const int chunk = (wv << 4) + i;
        const int rt = chunk >> 3, kc = (chunk >> 1) & 3, hl = chunk & 1;
        const _Float16* src = (hl ? Alg : Ahg) +
            ((((size_t)((mt << 3) + rt) * 32 + kf0 + kc) << 9) + ((size_t)lane << 3));
        __builtin_amdgcn_global_load_lds(
            (const __attribute__((address_space(1))) void*)src,
            (__attribute__((address_space(3))) void*)&Ash[(size_t)chunk << 9],
            16, 0, 0);
    }
    __syncthreads();

    const int ct0 = nt * 8 + (wn << 2);
    const _Float16* pBh = Bhg + ((((size_t)ct0 * 32 + kf0) * 64 + lane) << 3);
    const _Float16* pBl = Blg + ((((size_t)ct0 * 32 + kf0) * 64 + lane) << 3);

    floatx4 acc[4][4] = {};
    #pragma unroll
    for (int s = 0; s < 4; ++s) {
        half8 bhf[4], blf[4];
        #pragma unroll
        for (int j = 0; j < 4; ++j) {
            bhf[j] = *(const half8*)(pBh + ((size_t)j << 14) + ((size_t)s << 9));
            blf[j] = *(const half8*)(pBl + ((size_t)j << 14) + ((size_t)s << 9));
        }
        half8 ah[4], al[4];
        #pragma unroll
        for (int i = 0; i < 4; ++i) {
            const int rt = (wm << 2) + i;
            ah[i] = *(const half8*)&Ash[((((rt << 2) + s) << 1) << 9) + (lane << 3)];
            al[i] = *(const half8*)&Ash[(((((rt << 2) + s) << 1) + 1) << 9) + (lane << 3)];
        }
        #pragma unroll
        for (int i = 0; i < 4; ++i)
            #pragma unroll
            for (int j = 0; j < 4; ++j) {
                acc[i][j] = __builtin_amdgcn_mfma_f32_16x16x32_f16(
                    ah[i], blf[j], acc[i][j], 0, 0, 0);
                acc[i][j] = __builtin_amdgcn_mfma_f32_16x16x32_f16(
                    al[i], bhf[j], acc[i][j], 0, 0, 0);
                acc[i][j] = __builtin_amdgcn_mfma_f32_16x16x32_f16(
                    ah[i], bhf[j], acc[i][j], 0, 0, 0);
            }
    }

    const int orow = (lane >> 4) << 2;
    #pragma unroll
    for (int i = 0; i < 4; ++i) {
        const int gr = (mt << 7) + (wm << 6) + (i << 4) + orow;
        #pragma unroll
        for (int j = 0; j < 4; ++j) {
            const int gc = nt * 128 + (wn << 6) + (j << 4) + (lane & 15);
            #pragma unroll
            for (int r = 0; r < 4; ++r)
                atomicAdd(&out[(size_t)(gr + r) * NSTR + gc], acc[i][j][r]);
        }
    }
}

// ---------------------------------------------------------------------------
extern "C" void kernel_launch(void* const* d_in, const int* in_sizes, int n_in,
                              void* d_out, int out_size, void* d_ws, size_t ws_size,
                              hipStream_t stream) {
    const float* x    = (const float*)d_in[0];
    const float* w    = (const float*)d_in[1];
    const float* Minv = (const float*)d_in[2];

    float* enc = (float*)d_out;          // encoded: 1024*1024
    float* dec = enc + MM;               // decoded: 1024*512

    // ws (floats): adb MM | t MM | xkp 2*MM | halves: bh,bl,Th,Tl,ench,encl MM,
    // wsh,wsl MM/2 | solved[1024] + barrier words. ~30 MB. (unchanged layout)
    float* ws  = (float*)d_ws;
    float* adb = ws;
    float* t   = ws + (size_t)MM;
    float* xkp = ws + 2 * (size_t)MM;

    _Float16* bh   = (_Float16*)(ws + 4 * (size_t)MM);
    _Float16* bl   = bh + (size_t)MM;
    _Float16* Th   = bl + (size_t)MM;
    _Float16* Tl   = Th + (size_t)MM;
    _Float16* ench = Tl + (size_t)MM;
    _Float16* encl = ench + (size_t)MM;
    _Float16* wsh  = encl + (size_t)MM;
    _Float16* wsl  = wsh + (size_t)(NIN * MOUT);
    int* solved    = (int*)(wsl + (size_t)(NIN * MOUT));
    int* bar       = solved + 1088;      // 8 stripes x 32 ints (128 B) apart

    zero_init<<<(MM + 255) / 256, 256, 0, stream>>>(t, enc, dec, (float*)ench,
                                                    (float*)encl, solved);
    split_minv<<<512, 256, 0, stream>>>(Minv, Th, Tl);
    split_w<<<256, 256, 0, stream>>>(w, wsh, wsl);
    gemm_adb<<<256, 256, 0, stream>>>(x, w, adb, bh, bl);

    void* cargs[] = {(void*)&adb, (void*)&xkp, (void*)&t,
                     (void*)&bh,  (void*)&bl,  (void*)&Th, (void*)&Tl,
                     (void*)&enc, (void*)&ench, (void*)&encl, (void*)&solved,
                     (void*)&bar};
    // Cooperative launch used ONLY as a co-residency guarantee (deadlock
    // safety for the spin barriers); no grid.sync() is ever called.
    hipError_t e = hipLaunchCooperativeKernel(
        reinterpret_cast<void*>(admm_loop), dim3(512), dim3(256), cargs, 0, stream);
    if (e != hipSuccess) {
        // fallback: classic 2-kernel iteration loop
        for (int it = 0; it < MAX_ITERS; ++it) {
            gemm_xk<<<512, 256, 0, stream>>>(bh, bl, Th, Tl, xkp, solved);
            update<<<256, 256, 0, stream>>>(adb, xkp, t, bh, bl, enc, ench, encl,
                                            solved);
        }
    }

    mfma_dec<<<256, 256, 0, stream>>>(ench, encl, wsh, wsl, dec);
}